// Round 4
// baseline (3447.675 us; speedup 1.0000x reference)
//
#include <hip/hip_runtime.h>

// NeuralODE RK4: 10 steps x 4 stages x 3 GEMMs (8192x1024x1024), bf16 MFMA.
// GEMM: 256x128 tile, BK=64, 8 waves (128x32 each), 32x32x16 MFMA,
// 3 LDS buffers, 2-tile-ahead counted vmcnt(6), per-phase stage split,
// uniform-slot XOR swizzle, raw s_barrier + lgkmcnt(0) + sched_barrier,
// setprio around MFMA, LDS-staged vectorized epilogue. bf16 ksum RK4 state.

typedef __attribute__((ext_vector_type(8))) __bf16 bf16x8;
typedef __attribute__((ext_vector_type(16))) float f32x16;
typedef __attribute__((ext_vector_type(8))) float f32x8;
typedef __attribute__((ext_vector_type(8))) unsigned short us8;
typedef unsigned short ushort_t;

#define GLOAD16(gp, lp) \
  __builtin_amdgcn_global_load_lds((const __attribute__((address_space(1))) unsigned int*)(gp), \
                                   (__attribute__((address_space(3))) unsigned int*)(lp), 16, 0, 0)

__device__ __forceinline__ ushort_t f2bf(float f) {
  union { float f; unsigned u; } v; v.f = f;
  unsigned r = v.u + 0x7fffu + ((v.u >> 16) & 1u);   // RNE
  return (ushort_t)(r >> 16);
}
__device__ __forceinline__ float b2f(ushort_t u) {
  union { unsigned u; float f; } v; v.u = ((unsigned)u) << 16; return v.f;
}
__device__ __forceinline__ float fast_tanh(float x) {
  float e = __expf(2.0f * x);
  return 1.0f - 2.0f * __builtin_amdgcn_rcpf(e + 1.0f);
}

// ---------------- weight transpose (K x N fp32 -> N x K bf16) ----------------
__global__ void transpose_bf16(const float* __restrict__ in, ushort_t* __restrict__ out) {
  __shared__ float tile[32][33];
  const int bx = blockIdx.x * 32, by = blockIdx.y * 32;
  const int tx = threadIdx.x, ty = threadIdx.y;
#pragma unroll
  for (int i = 0; i < 32; i += 8)
    tile[ty + i][tx] = in[(size_t)(by + ty + i) * 1024 + bx + tx];
  __syncthreads();
#pragma unroll
  for (int i = 0; i < 32; i += 8)
    out[(size_t)(bx + ty + i) * 1024 + by + tx] = f2bf(tile[tx][ty + i]);
}

// ---------------- fp32 -> bf16 convert (initial h -> hb) ----------------
__global__ void conv_bf16(const float* __restrict__ in, ushort_t* __restrict__ out) {
  size_t i = ((size_t)blockIdx.x * 256 + threadIdx.x) * 4;
  float4 v = *(const float4*)&in[i];
  ushort4 o;
  o.x = f2bf(v.x); o.y = f2bf(v.y); o.z = f2bf(v.z); o.w = f2bf(v.w);
  *(ushort4*)&out[i] = o;
}

// ---------------- fused GEMM ----------------
// C[MxN] = A[MxK] * Bt[NxK]^T, A/Bt bf16 row-major. M=8192, N=K=1024.
// MODE 1: Xout = bf16(tanh(C + bias + tval*wlast))
// MODE 2: Xout = bf16(tanh(C + bias))
// MODE 3: kv = bf16(C + bias); RK4 stage S (dt=0.1):
//   S0: ksum = kv;            Xout = bf(hb + dt/2*kv)
//   S1: ksum += 2kv;          Xout = bf(hb + dt/2*kv)
//   S2: ksum += 2kv;          Xout = bf(hb + dt*kv)
//   S3: hn = h0 + dt/6*(ksum + kv); h1 = hn; Xout(=hb) = bf(hn)
template<int MODE, int S>
__global__ void __launch_bounds__(512, 1)
gemm_fused(const ushort_t* __restrict__ Ag, const ushort_t* __restrict__ Bg,
           const float* __restrict__ bias, const float* __restrict__ wlast, float tval,
           ushort_t* __restrict__ Xout, ushort_t* __restrict__ ksum,
           const ushort_t* __restrict__ hbr,
           const float* __restrict__ h0, float* __restrict__ h1)
{
  constexpr int NCOL = 1024, NT = 16;  // BK=64
  constexpr float DT = 0.1f;
  // per buffer: A 256x64 (16384 el, 32KB) | B 128x64 (8192 el, 16KB) = 48KB
  __shared__ __align__(16) ushort_t lds[3][24576];

  // 256 blocks = 32 bm x 8 bn. XCD x owns logicals [32x,32x+32):
  // 4 A-panels (2MB) + full B (2MB) per XCD L2; same-rows blocks co-XCD
  // across kernels (producer/consumer L2 locality).
  const int bid = blockIdx.x;
  const int logical = (bid & 7) * 32 + (bid >> 3);
  const int bm0 = (logical >> 3) * 256;
  const int bn0 = (logical & 7) * 128;

  const int tid = threadIdx.x;
  const int w = tid >> 6, l = tid & 63;
  const int wr = w >> 2, wn = w & 3;          // 2M x 4N waves -> 128x32 per wave

  // ---- staging: 6 gloads/thread/K-tile (4 A + 2 B), slot-swizzled source ----
  const int srow8 = l >> 3;                   // 0..7
  const int skc = (l & 7) ^ srow8;            // source k-chunk (uniform-slot swz)
  const ushort_t* gA = Ag + (size_t)(bm0 + w * 32 + srow8) * 1024 + skc * 8;
  const ushort_t* gB = Bg + (size_t)(bn0 + w * 16 + srow8) * 1024 + skc * 8;
  const unsigned lA = w * 2048 + l * 8;       // elem offset in buf (A: rows w*32..+32)
  const unsigned lB = 16384 + w * 1024 + l * 8;

#define SA(s, t1, i) GLOAD16(gA + (size_t)(i) * 8192 + (t1) * 64, &lds[s][lA + (i) * 512])
#define SB(s, t1, i) GLOAD16(gB + (size_t)(i) * 8192 + (t1) * 64, &lds[s][lB + (i) * 512])

  // ---- fragment addressing: elem(row,kc) at row*64 + (kc ^ (row&7))*8 ----
  const int lr31 = l & 31, kg = l >> 5, x7 = lr31 & 7;
  const int aB0 = (wr * 128 + lr31) * 64;     // + m*2048 + physchunk*8
  const int bB0 = 16384 + (wn * 32 + lr31) * 64;

  f32x16 acc[4];
#pragma unroll
  for (int m = 0; m < 4; ++m)
#pragma unroll
    for (int i = 0; i < 16; ++i) acc[m][i] = 0.f;

  // prologue: stage tiles 0,1 fully; tile 0 resident before loop
  SA(0, 0, 0); SA(0, 0, 1); SA(0, 0, 2); SA(0, 0, 3); SB(0, 0, 0); SB(0, 0, 1);
  SA(1, 1, 0); SA(1, 1, 1); SA(1, 1, 2); SA(1, 1, 3); SB(1, 1, 0); SB(1, 1, 1);
  asm volatile("s_waitcnt vmcnt(6)" ::: "memory");
  __builtin_amdgcn_s_barrier();
  __builtin_amdgcn_sched_barrier(0);

  int buf = 0;
#pragma unroll 1
  for (int t = 0; t < NT; ++t) {
    int s2 = buf + 2; if (s2 >= 3) s2 -= 3;   // buffer for tile t+2
    const ushort_t* Lb = &lds[buf][0];
    bf16x8 a0, a1, a2, a3, a4, a5, a6, a7, b0, b1;

    // ================ phase 0: kq 0,1 ================
    {
      const int c0 = ((0 + kg) ^ x7) * 8;     // kq=0 -> chunks kg
      const int c1 = ((2 + kg) ^ x7) * 8;     // kq=1 -> chunks 2+kg
      a0 = *(const bf16x8*)(Lb + aB0 + c0);
      a1 = *(const bf16x8*)(Lb + aB0 + 2048 + c0);
      a2 = *(const bf16x8*)(Lb + aB0 + 4096 + c0);
      a3 = *(const bf16x8*)(Lb + aB0 + 6144 + c0);
      a4 = *(const bf16x8*)(Lb + aB0 + c1);
      a5 = *(const bf16x8*)(Lb + aB0 + 2048 + c1);
      a6 = *(const bf16x8*)(Lb + aB0 + 4096 + c1);
      a7 = *(const bf16x8*)(Lb + aB0 + 6144 + c1);
      b0 = *(const bf16x8*)(Lb + bB0 + c0);
      b1 = *(const bf16x8*)(Lb + bB0 + c1);
    }
    if (t < NT - 2) { SA(s2, t + 2, 0); SA(s2, t + 2, 1); SA(s2, t + 2, 2); }
    __builtin_amdgcn_s_barrier();
    asm volatile("s_waitcnt lgkmcnt(0)" ::: "memory");
    __builtin_amdgcn_sched_barrier(0);
    __builtin_amdgcn_s_setprio(1);
    acc[0] = __builtin_amdgcn_mfma_f32_32x32x16_bf16(a0, b0, acc[0], 0, 0, 0);
    acc[1] = __builtin_amdgcn_mfma_f32_32x32x16_bf16(a1, b0, acc[1], 0, 0, 0);
    acc[2] = __builtin_amdgcn_mfma_f32_32x32x16_bf16(a2, b0, acc[2], 0, 0, 0);
    acc[3] = __builtin_amdgcn_mfma_f32_32x32x16_bf16(a3, b0, acc[3], 0, 0, 0);
    acc[0] = __builtin_amdgcn_mfma_f32_32x32x16_bf16(a4, b1, acc[0], 0, 0, 0);
    acc[1] = __builtin_amdgcn_mfma_f32_32x32x16_bf16(a5, b1, acc[1], 0, 0, 0);
    acc[2] = __builtin_amdgcn_mfma_f32_32x32x16_bf16(a6, b1, acc[2], 0, 0, 0);
    acc[3] = __builtin_amdgcn_mfma_f32_32x32x16_bf16(a7, b1, acc[3], 0, 0, 0);
    __builtin_amdgcn_s_setprio(0);
    __builtin_amdgcn_s_barrier();

    // ================ phase 1: kq 2,3 ================
    {
      const int c2 = ((4 + kg) ^ x7) * 8;
      const int c3 = ((6 + kg) ^ x7) * 8;
      a0 = *(const bf16x8*)(Lb + aB0 + c2);
      a1 = *(const bf16x8*)(Lb + aB0 + 2048 + c2);
      a2 = *(const bf16x8*)(Lb + aB0 + 4096 + c2);
      a3 = *(const bf16x8*)(Lb + aB0 + 6144 + c2);
      a4 = *(const bf16x8*)(Lb + aB0 + c3);
      a5 = *(const bf16x8*)(Lb + aB0 + 2048 + c3);
      a6 = *(const bf16x8*)(Lb + aB0 + 4096 + c3);
      a7 = *(const bf16x8*)(Lb + aB0 + 6144 + c3);
      b0 = *(const bf16x8*)(Lb + bB0 + c2);
      b1 = *(const bf16x8*)(Lb + bB0 + c3);
    }
    if (t < NT - 2) { SA(s2, t + 2, 3); SB(s2, t + 2, 0); SB(s2, t + 2, 1); }
    // tile t+1 must be resident for next iteration's phase-0 ds_reads
    if (t < NT - 2)       { asm volatile("s_waitcnt vmcnt(6)" ::: "memory"); }
    else if (t == NT - 2) { asm volatile("s_waitcnt vmcnt(0)" ::: "memory"); }
    __builtin_amdgcn_s_barrier();
    asm volatile("s_waitcnt lgkmcnt(0)" ::: "memory");
    __builtin_amdgcn_sched_barrier(0);
    __builtin_amdgcn_s_setprio(1);
    acc[0] = __builtin_amdgcn_mfma_f32_32x32x16_bf16(a0, b0, acc[0], 0, 0, 0);
    acc[1] = __builtin_amdgcn_mfma_f32_32x32x16_bf16(a1, b0, acc[1], 0, 0, 0);
    acc[2] = __builtin_amdgcn_mfma_f32_32x32x16_bf16(a2, b0, acc[2], 0, 0, 0);
    acc[3] = __builtin_amdgcn_mfma_f32_32x32x16_bf16(a3, b0, acc[3], 0, 0, 0);
    acc[0] = __builtin_amdgcn_mfma_f32_32x32x16_bf16(a4, b1, acc[0], 0, 0, 0);
    acc[1] = __builtin_amdgcn_mfma_f32_32x32x16_bf16(a5, b1, acc[1], 0, 0, 0);
    acc[2] = __builtin_amdgcn_mfma_f32_32x32x16_bf16(a6, b1, acc[2], 0, 0, 0);
    acc[3] = __builtin_amdgcn_mfma_f32_32x32x16_bf16(a7, b1, acc[3], 0, 0, 0);
    __builtin_amdgcn_s_setprio(0);
    __builtin_amdgcn_s_barrier();

    ++buf; if (buf == 3) buf = 0;
  }
#undef SA
#undef SB

  // ---- epilogue: stage C (bf16) through LDS, 16B-coalesced global I/O ----
  // C/D layout (32x32): col = lane&31, row = (reg&3) + 8*(reg>>2) + 4*(lane>>5)
  __syncthreads();
  ushort_t* C = &lds[0][0];                   // 256 x 136 bf16 = 68KB
  const int ecol = wn * 32 + lr31;            // one column per thread
  {
    const float bvx = bias[bn0 + ecol];
    const float add = (MODE == 1) ? (bvx + tval * wlast[bn0 + ecol]) : bvx;
#pragma unroll
    for (int m = 0; m < 4; ++m) {
#pragma unroll
      for (int reg = 0; reg < 16; ++reg) {
        const int lrow = wr * 128 + m * 32 + (reg & 3) + 8 * (reg >> 2) + 4 * kg;
        const float v = acc[m][reg] + add;
        C[lrow * 136 + ecol] = (MODE == 3) ? f2bf(v) : f2bf(fast_tanh(v));
      }
    }
  }
  __syncthreads();

#pragma unroll
  for (int i = 0; i < 8; ++i) {
    const int chunk = tid + i * 512;          // 4096 chunks of 8 elems
    const int row = chunk >> 4;
    const int cc = chunk & 15;
    const us8 kv8 = *(const us8*)&C[row * 136 + cc * 8];
    const size_t gidx = (size_t)(bm0 + row) * NCOL + bn0 + cc * 8;
    if (MODE != 3) {
      *(us8*)&Xout[gidx] = kv8;
    } else if (S == 0) {
      *(us8*)&ksum[gidx] = kv8;
      const us8 hb8 = *(const us8*)&hbr[gidx];
      us8 o;
#pragma unroll
      for (int e = 0; e < 8; ++e) o[e] = f2bf(b2f(hb8[e]) + (DT * 0.5f) * b2f(kv8[e]));
      *(us8*)&Xout[gidx] = o;
    } else if (S == 1 || S == 2) {
      const us8 ks8 = *(const us8*)&ksum[gidx];
      const us8 hb8 = *(const us8*)&hbr[gidx];
      us8 nks, o;
      const float c = (S == 1) ? (DT * 0.5f) : DT;
#pragma unroll
      for (int e = 0; e < 8; ++e) {
        const float kv = b2f(kv8[e]);
        nks[e] = f2bf(b2f(ks8[e]) + 2.f * kv);
        o[e] = f2bf(b2f(hb8[e]) + c * kv);
      }
      *(us8*)&ksum[gidx] = nks;
      *(us8*)&Xout[gidx] = o;
    } else {
      const us8 ks8 = *(const us8*)&ksum[gidx];
      const f32x8 h8 = *(const f32x8*)&h0[gidx];
      f32x8 hn; us8 o;
#pragma unroll
      for (int e = 0; e < 8; ++e) {
        hn[e] = h8[e] + (DT / 6.f) * (b2f(ks8[e]) + b2f(kv8[e]));
        o[e] = f2bf(hn[e]);
      }
      *(f32x8*)&h1[gidx] = hn;
      *(us8*)&Xout[gidx] = o;
    }
  }
}

extern "C" void kernel_launch(void* const* d_in, const int* in_sizes, int n_in,
                              void* d_out, int out_size, void* d_ws, size_t ws_size,
                              hipStream_t stream) {
  (void)in_sizes; (void)n_in; (void)out_size; (void)ws_size;
  const float* h_in = (const float*)d_in[0];
  const float* W1   = (const float*)d_in[1];   // 1025 x 1024
  const float* b1   = (const float*)d_in[2];
  const float* W2   = (const float*)d_in[3];
  const float* b2   = (const float*)d_in[4];
  const float* W3   = (const float*)d_in[5];
  const float* b3   = (const float*)d_in[6];

  char* ws = (char*)d_ws;
  ushort_t* W1t  = (ushort_t*)(ws);                        // 2 MiB
  ushort_t* W2t  = (ushort_t*)(ws + (2ull << 20));         // 2 MiB
  ushort_t* W3t  = (ushort_t*)(ws + (4ull << 20));         // 2 MiB
  ushort_t* hb   = (ushort_t*)(ws + (6ull << 20));         // 16 MiB bf16 h
  ushort_t* X1   = (ushort_t*)(ws + (22ull << 20));        // 16 MiB
  ushort_t* X2   = (ushort_t*)(ws + (38ull << 20));        // 16 MiB
  ushort_t* Xs   = (ushort_t*)(ws + (54ull << 20));        // 16 MiB stage input
  ushort_t* KS   = (ushort_t*)(ws + (70ull << 20));        // 16 MiB bf16 ksum
  float*    OUT  = (float*)d_out;                          // fp32 h (in-place)

  dim3 tb(32, 8);
  dim3 tg(32, 32);
  transpose_bf16<<<tg, tb, 0, stream>>>(W1, W1t);
  transpose_bf16<<<tg, tb, 0, stream>>>(W2, W2t);
  transpose_bf16<<<tg, tb, 0, stream>>>(W3, W3t);
  conv_bf16<<<8192, 256, 0, stream>>>(h_in, hb);

  const float dt = 0.1f;
  const float* W1last = W1 + (size_t)1024 * 1024;
  constexpr int GRID = 256, BLK = 512;

  for (int step = 0; step < 10; ++step) {
    const float t0 = step * dt;
    const float* h0p = (step == 0) ? h_in : (const float*)OUT;

    // stage 0 (t = t0), A = hb
    gemm_fused<1, 0><<<GRID, BLK, 0, stream>>>(hb, W1t, b1, W1last, t0, X1, nullptr, nullptr, nullptr, nullptr);
    gemm_fused<2, 0><<<GRID, BLK, 0, stream>>>(X1, W2t, b2, nullptr, 0.f, X2, nullptr, nullptr, nullptr, nullptr);
    gemm_fused<3, 0><<<GRID, BLK, 0, stream>>>(X2, W3t, b3, nullptr, 0.f, Xs, KS, hb, nullptr, nullptr);

    // stage 1 (t = t0 + dt/2), A = Xs
    gemm_fused<1, 0><<<GRID, BLK, 0, stream>>>(Xs, W1t, b1, W1last, t0 + 0.5f * dt, X1, nullptr, nullptr, nullptr, nullptr);
    gemm_fused<2, 0><<<GRID, BLK, 0, stream>>>(X1, W2t, b2, nullptr, 0.f, X2, nullptr, nullptr, nullptr, nullptr);
    gemm_fused<3, 1><<<GRID, BLK, 0, stream>>>(X2, W3t, b3, nullptr, 0.f, Xs, KS, hb, nullptr, nullptr);

    // stage 2 (t = t0 + dt/2)
    gemm_fused<1, 0><<<GRID, BLK, 0, stream>>>(Xs, W1t, b1, W1last, t0 + 0.5f * dt, X1, nullptr, nullptr, nullptr, nullptr);
    gemm_fused<2, 0><<<GRID, BLK, 0, stream>>>(X1, W2t, b2, nullptr, 0.f, X2, nullptr, nullptr, nullptr, nullptr);
    gemm_fused<3, 2><<<GRID, BLK, 0, stream>>>(X2, W3t, b3, nullptr, 0.f, Xs, KS, hb, nullptr, nullptr);

    // stage 3 (t = t0 + dt); S3 writes h1 (in-place OUT) + hb
    gemm_fused<1, 0><<<GRID, BLK, 0, stream>>>(Xs, W1t, b1, W1last, t0 + dt, X1, nullptr, nullptr, nullptr, nullptr);
    gemm_fused<2, 0><<<GRID, BLK, 0, stream>>>(X1, W2t, b2, nullptr, 0.f, X2, nullptr, nullptr, nullptr, nullptr);
    gemm_fused<3, 3><<<GRID, BLK, 0, stream>>>(X2, W3t, b3, nullptr, 0.f, hb, KS, nullptr, h0p, OUT);
  }
}

// Round 5
// 3045.831 us; speedup vs baseline: 1.1319x; 1.1319x over previous
//
#include <hip/hip_runtime.h>

// NeuralODE RK4: 10 steps x 4 stages x 3 GEMMs (8192x1024x1024), bf16 MFMA.
// GEMM: 256x128 tile, BK=64, 8 waves as 4Mx2N (64x64/wave), 3 LDS buffers
// (144KB, 1 block/CU), m201-style 4 fine phases per K-tile (8 MFMA each),
// counted vmcnt(6), XOR-swizzled LDS via pre-swizzled global source,
// raw s_barrier + lgkmcnt(0) + sched_barrier(0), setprio around MFMA,
// LDS-staged vectorized epilogue. bf16 ksum RK4 state.

typedef __attribute__((ext_vector_type(8))) __bf16 bf16x8;
typedef __attribute__((ext_vector_type(4))) float f32x4;
typedef __attribute__((ext_vector_type(8))) float f32x8;
typedef __attribute__((ext_vector_type(8))) unsigned short us8;
typedef unsigned short ushort_t;

#define GLOAD16(gp, lp) \
  __builtin_amdgcn_global_load_lds((const __attribute__((address_space(1))) unsigned int*)(gp), \
                                   (__attribute__((address_space(3))) unsigned int*)(lp), 16, 0, 0)

__device__ __forceinline__ ushort_t f2bf(float f) {
  union { float f; unsigned u; } v; v.f = f;
  unsigned r = v.u + 0x7fffu + ((v.u >> 16) & 1u);   // RNE
  return (ushort_t)(r >> 16);
}
__device__ __forceinline__ float b2f(ushort_t u) {
  union { unsigned u; float f; } v; v.u = ((unsigned)u) << 16; return v.f;
}
__device__ __forceinline__ float fast_tanh(float x) {
  float e = __expf(2.0f * x);
  return 1.0f - 2.0f * __builtin_amdgcn_rcpf(e + 1.0f);
}

// ---------------- weight transpose (K x N fp32 -> N x K bf16) ----------------
__global__ void transpose_bf16(const float* __restrict__ in, ushort_t* __restrict__ out) {
  __shared__ float tile[32][33];
  const int bx = blockIdx.x * 32, by = blockIdx.y * 32;
  const int tx = threadIdx.x, ty = threadIdx.y;
#pragma unroll
  for (int i = 0; i < 32; i += 8)
    tile[ty + i][tx] = in[(size_t)(by + ty + i) * 1024 + bx + tx];
  __syncthreads();
#pragma unroll
  for (int i = 0; i < 32; i += 8)
    out[(size_t)(bx + ty + i) * 1024 + by + tx] = f2bf(tile[tx][ty + i]);
}

// ---------------- fp32 -> bf16 convert (initial h -> hb) ----------------
__global__ void conv_bf16(const float* __restrict__ in, ushort_t* __restrict__ out) {
  size_t i = ((size_t)blockIdx.x * 256 + threadIdx.x) * 4;
  float4 v = *(const float4*)&in[i];
  ushort4 o;
  o.x = f2bf(v.x); o.y = f2bf(v.y); o.z = f2bf(v.z); o.w = f2bf(v.w);
  *(ushort4*)&out[i] = o;
}

// ---------------- fused GEMM ----------------
// C[MxN] = A[MxK] * Bt[NxK]^T, A/Bt bf16 row-major. M=8192, N=K=1024.
// MODE 1: Xout = bf16(tanh(C + bias + tval*wlast))
// MODE 2: Xout = bf16(tanh(C + bias))
// MODE 3: kv = bf16(C + bias); RK4 stage S (dt=0.1):
//   S0: ksum = kv;            Xout = bf(hb + dt/2*kv)
//   S1: ksum += 2kv;          Xout = bf(hb + dt/2*kv)
//   S2: ksum += 2kv;          Xout = bf(hb + dt*kv)
//   S3: hn = h0 + dt/6*(ksum + kv); h1 = hn; Xout(=hb) = bf(hn)
template<int MODE, int S>
__global__ void __launch_bounds__(512, 1)
gemm_fused(const ushort_t* __restrict__ Ag, const ushort_t* __restrict__ Bg,
           const float* __restrict__ bias, const float* __restrict__ wlast, float tval,
           ushort_t* __restrict__ Xout, ushort_t* __restrict__ ksum,
           const ushort_t* __restrict__ hbr,
           const float* __restrict__ h0, float* __restrict__ h1)
{
  constexpr int NCOL = 1024, NT = 16;  // BK=64
  constexpr float DT = 0.1f;
  // per buffer: A 256x64 (16384 el, 32KB) | B 128x64 (8192 el, 16KB) = 48KB
  __shared__ __align__(16) ushort_t lds[3][24576];

  // 256 blocks = 32 bm x 8 bn. XCD x owns logicals [32x,32x+32):
  // 4 A-panels (2MB) + full B (2MB) per XCD L2; same-rows co-XCD across
  // dependent kernels (producer/consumer L2 locality).
  const int bid = blockIdx.x;
  const int logical = (bid & 7) * 32 + (bid >> 3);
  const int bm0 = (logical >> 3) * 256;
  const int bn0 = (logical & 7) * 128;

  const int tid = threadIdx.x;
  const int w = tid >> 6, l = tid & 63;
  const int wr = w >> 1, wc = w & 1;          // 4M x 2N waves -> 64x64 per wave

  // ---- staging: 6 gloads/thread/K-tile (4 A + 2 B), pre-swizzled source ----
  const int srow8 = l >> 3;                   // 0..7
  const int skc = (l & 7) ^ srow8;            // source k-chunk (inverse swizzle)
  const ushort_t* gA = Ag + (size_t)(bm0 + w * 32 + srow8) * 1024 + skc * 8;
  const ushort_t* gB = Bg + (size_t)(bn0 + w * 16 + srow8) * 1024 + skc * 8;
  const unsigned lA = w * 2048 + l * 8;       // elem offset (A rows w*32..+32)
  const unsigned lB = 16384 + w * 1024 + l * 8;

#define SA(s, t1, i) GLOAD16(gA + (size_t)(i) * 8192 + (t1) * 64, &lds[s][lA + (i) * 512])
#define SB(s, t1, i) GLOAD16(gB + (size_t)(i) * 8192 + (t1) * 64, &lds[s][lB + (i) * 512])

  // ---- fragment addressing: elem(row,kc) at row*64 + (kc ^ (row&7))*8 ----
  const int r16 = l & 15, kb = l >> 4, x7 = r16 & 7;
  const int aR = (wr * 64 + r16) * 64;        // + mq*1024 + physchunk*8
  const int bR = 16384 + (wc * 64 + r16) * 64;   // + nq*1024 + physchunk*8
  const int c0 = (kb ^ x7) * 8;               // ks=0 chunk offset
  const int c1 = ((4 | kb) ^ x7) * 8;         // ks=1 chunk offset

  f32x4 acc[4][4];
#pragma unroll
  for (int m = 0; m < 4; ++m)
#pragma unroll
    for (int n = 0; n < 4; ++n) acc[m][n] = (f32x4){0.f, 0.f, 0.f, 0.f};

  // prologue: stage tiles 0,1; tile 0 resident before loop
  SA(0, 0, 0); SA(0, 0, 1); SA(0, 0, 2); SA(0, 0, 3); SB(0, 0, 0); SB(0, 0, 1);
  SA(1, 1, 0); SA(1, 1, 1); SA(1, 1, 2); SA(1, 1, 3); SB(1, 1, 0); SB(1, 1, 1);
  asm volatile("s_waitcnt vmcnt(6)" ::: "memory");
  __builtin_amdgcn_s_barrier();
  __builtin_amdgcn_sched_barrier(0);

#define MFMA_PAIR(aX, aY, mi, mj) do { \
    acc[mi][0] = __builtin_amdgcn_mfma_f32_16x16x32_bf16(aX, b0, acc[mi][0], 0, 0, 0); \
    acc[mi][1] = __builtin_amdgcn_mfma_f32_16x16x32_bf16(aX, b1, acc[mi][1], 0, 0, 0); \
    acc[mi][2] = __builtin_amdgcn_mfma_f32_16x16x32_bf16(aX, b2, acc[mi][2], 0, 0, 0); \
    acc[mi][3] = __builtin_amdgcn_mfma_f32_16x16x32_bf16(aX, b3, acc[mi][3], 0, 0, 0); \
    acc[mj][0] = __builtin_amdgcn_mfma_f32_16x16x32_bf16(aY, b0, acc[mj][0], 0, 0, 0); \
    acc[mj][1] = __builtin_amdgcn_mfma_f32_16x16x32_bf16(aY, b1, acc[mj][1], 0, 0, 0); \
    acc[mj][2] = __builtin_amdgcn_mfma_f32_16x16x32_bf16(aY, b2, acc[mj][2], 0, 0, 0); \
    acc[mj][3] = __builtin_amdgcn_mfma_f32_16x16x32_bf16(aY, b3, acc[mj][3], 0, 0, 0); \
  } while (0)

#define PH_SYNC() do { \
    __builtin_amdgcn_s_barrier(); \
    asm volatile("s_waitcnt lgkmcnt(0)" ::: "memory"); \
    __builtin_amdgcn_sched_barrier(0); \
  } while (0)

  int buf = 0;
#pragma unroll 1
  for (int t = 0; t < NT; ++t) {
    int s2 = buf + 2; if (s2 >= 3) s2 -= 3;   // buffer for tile t+2
    const ushort_t* Lb = &lds[buf][0];
    bf16x8 aA, aB, b0, b1, b2, b3;

    // ---- phase 0: ks=0, mq 0-1, all B(ks0) ----
    aA = *(const bf16x8*)(Lb + aR + c0);
    aB = *(const bf16x8*)(Lb + aR + 1024 + c0);
    b0 = *(const bf16x8*)(Lb + bR + c0);
    b1 = *(const bf16x8*)(Lb + bR + 1024 + c0);
    b2 = *(const bf16x8*)(Lb + bR + 2048 + c0);
    b3 = *(const bf16x8*)(Lb + bR + 3072 + c0);
    if (t < NT - 2) { SA(s2, t + 2, 0); SA(s2, t + 2, 1); }
    PH_SYNC();
    __builtin_amdgcn_s_setprio(1);
    MFMA_PAIR(aA, aB, 0, 1);
    __builtin_amdgcn_s_setprio(0);
    __builtin_amdgcn_s_barrier();

    // ---- phase 1: ks=0, mq 2-3 ----
    aA = *(const bf16x8*)(Lb + aR + 2048 + c0);
    aB = *(const bf16x8*)(Lb + aR + 3072 + c0);
    if (t < NT - 2) { SA(s2, t + 2, 2); SA(s2, t + 2, 3); }
    PH_SYNC();
    __builtin_amdgcn_s_setprio(1);
    MFMA_PAIR(aA, aB, 2, 3);
    __builtin_amdgcn_s_setprio(0);
    __builtin_amdgcn_s_barrier();

    // ---- phase 2: ks=1, mq 0-1, all B(ks1) ----
    aA = *(const bf16x8*)(Lb + aR + c1);
    aB = *(const bf16x8*)(Lb + aR + 1024 + c1);
    b0 = *(const bf16x8*)(Lb + bR + c1);
    b1 = *(const bf16x8*)(Lb + bR + 1024 + c1);
    b2 = *(const bf16x8*)(Lb + bR + 2048 + c1);
    b3 = *(const bf16x8*)(Lb + bR + 3072 + c1);
    if (t < NT - 2) { SB(s2, t + 2, 0); SB(s2, t + 2, 1); }
    PH_SYNC();
    __builtin_amdgcn_s_setprio(1);
    MFMA_PAIR(aA, aB, 0, 1);
    __builtin_amdgcn_s_setprio(0);
    __builtin_amdgcn_s_barrier();

    // ---- phase 3: ks=1, mq 2-3; tile t+1 residency gate ----
    aA = *(const bf16x8*)(Lb + aR + 2048 + c1);
    aB = *(const bf16x8*)(Lb + aR + 3072 + c1);
    if (t < NT - 2)       { asm volatile("s_waitcnt vmcnt(6)" ::: "memory"); }
    else if (t == NT - 2) { asm volatile("s_waitcnt vmcnt(0)" ::: "memory"); }
    PH_SYNC();
    __builtin_amdgcn_s_setprio(1);
    MFMA_PAIR(aA, aB, 2, 3);
    __builtin_amdgcn_s_setprio(0);
    __builtin_amdgcn_s_barrier();

    ++buf; if (buf == 3) buf = 0;
  }
#undef SA
#undef SB
#undef MFMA_PAIR
#undef PH_SYNC

  // ---- epilogue: stage C (bf16) through LDS, 16B-coalesced global I/O ----
  // C/D layout (16x16): col = lane&15, row = (lane>>4)*4 + reg
  __syncthreads();
  ushort_t* C = &lds[0][0];                   // 256 x 136 bf16 = 68KB
  const int er = (l >> 4) * 4;
  const int ec = l & 15;
#pragma unroll
  for (int n = 0; n < 4; ++n) {
    const int lc = wc * 64 + n * 16 + ec;
    const float bvx = bias[bn0 + lc];
    const float add = (MODE == 1) ? (bvx + tval * wlast[bn0 + lc]) : bvx;
#pragma unroll
    for (int m = 0; m < 4; ++m) {
#pragma unroll
      for (int j = 0; j < 4; ++j) {
        const int lr = wr * 64 + m * 16 + er + j;
        const float v = acc[m][n][j] + add;
        C[lr * 136 + lc] = (MODE == 3) ? f2bf(v) : f2bf(fast_tanh(v));
      }
    }
  }
  __syncthreads();

#pragma unroll
  for (int i = 0; i < 8; ++i) {
    const int chunk = tid + i * 512;          // 4096 chunks of 8 elems
    const int row = chunk >> 4;
    const int cc = chunk & 15;
    const us8 kv8 = *(const us8*)&C[row * 136 + cc * 8];
    const size_t gidx = (size_t)(bm0 + row) * NCOL + bn0 + cc * 8;
    if (MODE != 3) {
      *(us8*)&Xout[gidx] = kv8;
    } else if (S == 0) {
      *(us8*)&ksum[gidx] = kv8;
      const us8 hb8 = *(const us8*)&hbr[gidx];
      us8 o;
#pragma unroll
      for (int e = 0; e < 8; ++e) o[e] = f2bf(b2f(hb8[e]) + (DT * 0.5f) * b2f(kv8[e]));
      *(us8*)&Xout[gidx] = o;
    } else if (S == 1 || S == 2) {
      const us8 ks8 = *(const us8*)&ksum[gidx];
      const us8 hb8 = *(const us8*)&hbr[gidx];
      us8 nks, o;
      const float c = (S == 1) ? (DT * 0.5f) : DT;
#pragma unroll
      for (int e = 0; e < 8; ++e) {
        const float kv = b2f(kv8[e]);
        nks[e] = f2bf(b2f(ks8[e]) + 2.f * kv);
        o[e] = f2bf(b2f(hb8[e]) + c * kv);
      }
      *(us8*)&ksum[gidx] = nks;
      *(us8*)&Xout[gidx] = o;
    } else {
      const us8 ks8 = *(const us8*)&ksum[gidx];
      const f32x8 h8 = *(const f32x8*)&h0[gidx];
      f32x8 hn; us8 o;
#pragma unroll
      for (int e = 0; e < 8; ++e) {
        hn[e] = h8[e] + (DT / 6.f) * (b2f(ks8[e]) + b2f(kv8[e]));
        o[e] = f2bf(hn[e]);
      }
      *(f32x8*)&h1[gidx] = hn;
      *(us8*)&Xout[gidx] = o;
    }
  }
}

extern "C" void kernel_launch(void* const* d_in, const int* in_sizes, int n_in,
                              void* d_out, int out_size, void* d_ws, size_t ws_size,
                              hipStream_t stream) {
  (void)in_sizes; (void)n_in; (void)out_size; (void)ws_size;
  const float* h_in = (const float*)d_in[0];
  const float* W1   = (const float*)d_in[1];   // 1025 x 1024
  const float* b1   = (const float*)d_in[2];
  const float* W2   = (const float*)d_in[3];
  const float* b2   = (const float*)d_in[4];
  const float* W3   = (const float*)d_in[5];
  const float* b3   = (const float*)d_in[6];

  char* ws = (char*)d_ws;
  ushort_t* W1t  = (ushort_t*)(ws);                        // 2 MiB
  ushort_t* W2t  = (ushort_t*)(ws + (2ull << 20));         // 2 MiB
  ushort_t* W3t  = (ushort_t*)(ws + (4ull << 20));         // 2 MiB
  ushort_t* hb   = (ushort_t*)(ws + (6ull << 20));         // 16 MiB bf16 h
  ushort_t* X1   = (ushort_t*)(ws + (22ull << 20));        // 16 MiB
  ushort_t* X2   = (ushort_t*)(ws + (38ull << 20));        // 16 MiB
  ushort_t* Xs   = (ushort_t*)(ws + (54ull << 20));        // 16 MiB stage input
  ushort_t* KS   = (ushort_t*)(ws + (70ull << 20));        // 16 MiB bf16 ksum
  float*    OUT  = (float*)d_out;                          // fp32 h (in-place)

  dim3 tb(32, 8);
  dim3 tg(32, 32);
  transpose_bf16<<<tg, tb, 0, stream>>>(W1, W1t);
  transpose_bf16<<<tg, tb, 0, stream>>>(W2, W2t);
  transpose_bf16<<<tg, tb, 0, stream>>>(W3, W3t);
  conv_bf16<<<8192, 256, 0, stream>>>(h_in, hb);

  const float dt = 0.1f;
  const float* W1last = W1 + (size_t)1024 * 1024;
  constexpr int GRID = 256, BLK = 512;

  for (int step = 0; step < 10; ++step) {
    const float t0 = step * dt;
    const float* h0p = (step == 0) ? h_in : (const float*)OUT;

    // stage 0 (t = t0), A = hb
    gemm_fused<1, 0><<<GRID, BLK, 0, stream>>>(hb, W1t, b1, W1last, t0, X1, nullptr, nullptr, nullptr, nullptr);
    gemm_fused<2, 0><<<GRID, BLK, 0, stream>>>(X1, W2t, b2, nullptr, 0.f, X2, nullptr, nullptr, nullptr, nullptr);
    gemm_fused<3, 0><<<GRID, BLK, 0, stream>>>(X2, W3t, b3, nullptr, 0.f, Xs, KS, hb, nullptr, nullptr);

    // stage 1 (t = t0 + dt/2), A = Xs
    gemm_fused<1, 0><<<GRID, BLK, 0, stream>>>(Xs, W1t, b1, W1last, t0 + 0.5f * dt, X1, nullptr, nullptr, nullptr, nullptr);
    gemm_fused<2, 0><<<GRID, BLK, 0, stream>>>(X1, W2t, b2, nullptr, 0.f, X2, nullptr, nullptr, nullptr, nullptr);
    gemm_fused<3, 1><<<GRID, BLK, 0, stream>>>(X2, W3t, b3, nullptr, 0.f, Xs, KS, hb, nullptr, nullptr);

    // stage 2 (t = t0 + dt/2)
    gemm_fused<1, 0><<<GRID, BLK, 0, stream>>>(Xs, W1t, b1, W1last, t0 + 0.5f * dt, X1, nullptr, nullptr, nullptr, nullptr);
    gemm_fused<2, 0><<<GRID, BLK, 0, stream>>>(X1, W2t, b2, nullptr, 0.f, X2, nullptr, nullptr, nullptr, nullptr);
    gemm_fused<3, 2><<<GRID, BLK, 0, stream>>>(X2, W3t, b3, nullptr, 0.f, Xs, KS, hb, nullptr, nullptr);

    // stage 3 (t = t0 + dt); S3 writes h1 (in-place OUT) + hb
    gemm_fused<1, 0><<<GRID, BLK, 0, stream>>>(Xs, W1t, b1, W1last, t0 + dt, X1, nullptr, nullptr, nullptr, nullptr);
    gemm_fused<2, 0><<<GRID, BLK, 0, stream>>>(X1, W2t, b2, nullptr, 0.f, X2, nullptr, nullptr, nullptr, nullptr);
    gemm_fused<3, 3><<<GRID, BLK, 0, stream>>>(X2, W3t, b3, nullptr, 0.f, hb, KS, nullptr, h0p, OUT);
  }
}

// Round 6
// 2210.474 us; speedup vs baseline: 1.5597x; 1.3779x over previous
//
#include <hip/hip_runtime.h>

// NeuralODE RK4, algebraically restructured:
//   W31 = W3@W1a, c31 = b3@W1a precomputed ->  k@W1 = x2@W31 + c31,
//   so layer3-GEMM + next-stage layer1-GEMM merge. State kept as
//   hW1 = h@W1 (bf16, updated once per step); h reconstructed at the end via
//   h_final = h0 + dt/6 * XT@W3 + b3,  XT = sum over steps of (x2_1+2x2_2+2x2_3+x2_4).
// 81 8192x1024x1024 GEMMs (was 120). GEMM core = proven 128x128/BK64/
// 2-blocks-per-CU structure with XOR-swizzled LDS + global_load_lds.

typedef __attribute__((ext_vector_type(8))) __bf16 bf16x8;
typedef __attribute__((ext_vector_type(4))) float f32x4;
typedef __attribute__((ext_vector_type(8))) float f32x8;
typedef __attribute__((ext_vector_type(8))) unsigned short us8;
typedef unsigned short ushort_t;

#define GLOAD16(gp, lp) \
  __builtin_amdgcn_global_load_lds((const __attribute__((address_space(1))) unsigned int*)(gp), \
                                   (__attribute__((address_space(3))) unsigned int*)(lp), 16, 0, 0)

__device__ __forceinline__ ushort_t f2bf(float f) {
  union { float f; unsigned u; } v; v.f = f;
  unsigned r = v.u + 0x7fffu + ((v.u >> 16) & 1u);   // RNE
  return (ushort_t)(r >> 16);
}
__device__ __forceinline__ float b2f(ushort_t u) {
  union { unsigned u; float f; } v; v.u = ((unsigned)u) << 16; return v.f;
}
__device__ __forceinline__ float fast_tanh(float x) {
  float e = __expf(2.0f * x);
  return 1.0f - 2.0f * __builtin_amdgcn_rcpf(e + 1.0f);
}

// ---------------- weight transpose (K x N fp32 -> N x K bf16) ----------------
__global__ void transpose_bf16(const float* __restrict__ in, ushort_t* __restrict__ out) {
  __shared__ float tile[32][33];
  const int bx = blockIdx.x * 32, by = blockIdx.y * 32;
  const int tx = threadIdx.x, ty = threadIdx.y;
#pragma unroll
  for (int i = 0; i < 32; i += 8)
    tile[ty + i][tx] = in[(size_t)(by + ty + i) * 1024 + bx + tx];
  __syncthreads();
#pragma unroll
  for (int i = 0; i < 32; i += 8)
    out[(size_t)(bx + ty + i) * 1024 + by + tx] = f2bf(tile[tx][ty + i]);
}

// ---------------- fp32 -> bf16 convert ----------------
__global__ void conv_bf16(const float* __restrict__ in, ushort_t* __restrict__ out) {
  size_t i = ((size_t)blockIdx.x * 256 + threadIdx.x) * 4;
  float4 v = *(const float4*)&in[i];
  ushort4 o;
  o.x = f2bf(v.x); o.y = f2bf(v.y); o.z = f2bf(v.z); o.w = f2bf(v.w);
  *(ushort4*)&out[i] = o;
}

// ---------------- c31 = b3 @ W1a  (c31[j] = sum_k W1t[j][k]*b3[k]) ----------
__global__ void c31_kernel(const ushort_t* __restrict__ W1t, const float* __restrict__ b3,
                           float* __restrict__ c31) {
  const int j = blockIdx.x * 256 + threadIdx.x;
  float acc = 0.f;
  for (int c = 0; c < 128; ++c) {
    const us8 w = *(const us8*)&W1t[(size_t)j * 1024 + c * 8];
    const f32x8 b = *(const f32x8*)&b3[c * 8];
#pragma unroll
    for (int e = 0; e < 8; ++e) acc += b2f(w[e]) * b[e];
  }
  c31[j] = acc;
}

// ---------------- fused GEMM ----------------
// C[MxN] = A[MxK]*Bt[NxK]^T, A/Bt bf16 row-major, K=N=1024, M = gridDim/8*128.
// MODE 0: out0 = bf16(C)                                   (W31 precompute)
// MODE 1: out0 = bf16(C); out1 = tanh(C + b)               (initial hW1, x1; t=0)
// MODE 2: x2 = tanh(C + b); out0 = x2; XT(out1) = flag ? x2 : XT + p0*x2
// MODE 3: g = C; GS(out1) = flag ? g : GS + p0*g;
//         u = hW1(auxR1) + p1*(g + c31) + b + p2*wl; out0 = tanh(u)
// MODE 4: g = C; hn = hW1(auxR1) + DT/6*(GS(auxR2) + g) + DT*c31;
//         out1 = bf16(hn); out0 = tanh(hn + b + p2*wl)
// MODE 5: outf = h0f + DT/6*C + b                          (final fp32 h)
template<int MODE>
__global__ void __launch_bounds__(256, 2)
gemm_fused(const ushort_t* __restrict__ Ag, const ushort_t* __restrict__ Bg,
           const float* __restrict__ bias, const float* __restrict__ wl,
           const float* __restrict__ c31,
           const ushort_t* __restrict__ auxR1, const ushort_t* __restrict__ auxR2,
           ushort_t* __restrict__ out0, ushort_t* __restrict__ out1,
           float p0, float p1, float p2, int flag,
           const float* __restrict__ h0f, float* __restrict__ outf)
{
  constexpr int K = 1024, NCOL = 1024, NT = 16;  // BK=64
  constexpr float DT = 0.1f;
  __shared__ __align__(16) ushort_t lds[2][16384];

  // generic XCD swizzle (grid % 8 == 0): xcd owns contiguous logical range
  const int bid = blockIdx.x;
  const int nb = (int)gridDim.x >> 3;
  const int logical = (bid & 7) * nb + (bid >> 3);
  const int bm0 = (logical >> 3) * 128;
  const int bn0 = (logical & 7) * 128;

  const int tid = threadIdx.x;
  const int w = tid >> 6, l = tid & 63;
  const int wr = w >> 1, wc = w & 1;          // 2x2 waves -> 64x64 per wave

  // ---- staging (8 gloads/thread: 4 A + 4 B), pre-swizzled source ----
  const int srow = l >> 3;
  const int sclog = (l & 7) ^ srow;
  const size_t gA0 = (size_t)(bm0 + w * 32 + srow) * K + sclog * 8;
  const size_t gB0 = (size_t)(bn0 + w * 32 + srow) * K + sclog * 8;
  const int ldsAo = w * 2048 + l * 8;
  const int ldsBo = 8192 + w * 2048 + l * 8;

#define STAGE(s, t1) do { \
    const ushort_t* ga = Ag + gA0 + (size_t)(t1) * 64; \
    const ushort_t* gb = Bg + gB0 + (size_t)(t1) * 64; \
    GLOAD16(ga,          &lds[s][ldsAo]); \
    GLOAD16(ga + 8 * K,  &lds[s][ldsAo + 512]); \
    GLOAD16(ga + 16 * K, &lds[s][ldsAo + 1024]); \
    GLOAD16(ga + 24 * K, &lds[s][ldsAo + 1536]); \
    GLOAD16(gb,          &lds[s][ldsBo]); \
    GLOAD16(gb + 8 * K,  &lds[s][ldsBo + 512]); \
    GLOAD16(gb + 16 * K, &lds[s][ldsBo + 1024]); \
    GLOAD16(gb + 24 * K, &lds[s][ldsBo + 1536]); } while (0)

  // ---- fragment read addressing (phys chunk = logical ^ (row&7)) ----
  const int r = l & 15, kb = l >> 4, xr = r & 7;
  const int aRow = (wr * 64 + r) * 64;
  const int bRow = 8192 + (wc * 64 + r) * 64;
  const int c0 = ((0 | kb) ^ xr) * 8;
  const int c1 = ((4 | kb) ^ xr) * 8;

  f32x4 acc[4][4];
#pragma unroll
  for (int m = 0; m < 4; ++m)
#pragma unroll
    for (int n = 0; n < 4; ++n) acc[m][n] = (f32x4){0.f, 0.f, 0.f, 0.f};

  STAGE(0, 0);

  for (int t = 0; t < NT; ++t) {
    const int cur = t & 1;
    __builtin_amdgcn_s_barrier();
    if (t + 1 < NT) {
      STAGE(cur ^ 1, t + 1);
      asm volatile("s_waitcnt vmcnt(8)" ::: "memory");
    } else {
      asm volatile("s_waitcnt vmcnt(0)" ::: "memory");
    }
    __builtin_amdgcn_s_barrier();
    __builtin_amdgcn_sched_barrier(0);

    const ushort_t* Lb = &lds[cur][0];
    bf16x8 av[4], bv[4];
#pragma unroll
    for (int m = 0; m < 4; ++m) av[m] = *(const bf16x8*)(Lb + aRow + m * 1024 + c0);
#pragma unroll
    for (int n = 0; n < 4; ++n) bv[n] = *(const bf16x8*)(Lb + bRow + n * 1024 + c0);
    __builtin_amdgcn_s_setprio(1);
#pragma unroll
    for (int m = 0; m < 4; ++m)
#pragma unroll
      for (int n = 0; n < 4; ++n)
        acc[m][n] = __builtin_amdgcn_mfma_f32_16x16x32_bf16(av[m], bv[n], acc[m][n], 0, 0, 0);
    __builtin_amdgcn_s_setprio(0);
#pragma unroll
    for (int m = 0; m < 4; ++m) av[m] = *(const bf16x8*)(Lb + aRow + m * 1024 + c1);
#pragma unroll
    for (int n = 0; n < 4; ++n) bv[n] = *(const bf16x8*)(Lb + bRow + n * 1024 + c1);
    __builtin_amdgcn_s_setprio(1);
#pragma unroll
    for (int m = 0; m < 4; ++m)
#pragma unroll
      for (int n = 0; n < 4; ++n)
        acc[m][n] = __builtin_amdgcn_mfma_f32_16x16x32_bf16(av[m], bv[n], acc[m][n], 0, 0, 0);
    __builtin_amdgcn_s_setprio(0);
  }
#undef STAGE

  // ---- epilogue: stage raw bf16(C) through LDS, vectorized per-mode pass ----
  __syncthreads();
  ushort_t* C = &lds[0][0];                   // 128 x 136 bf16
  const int er = (l >> 4) * 4;
  const int ec = l & 15;
#pragma unroll
  for (int n = 0; n < 4; ++n) {
    const int lc = wc * 64 + n * 16 + ec;
#pragma unroll
    for (int m = 0; m < 4; ++m) {
#pragma unroll
      for (int j = 0; j < 4; ++j) {
        const int lr = wr * 64 + m * 16 + er + j;
        C[lr * 136 + lc] = f2bf(acc[m][n][j]);
      }
    }
  }
  __syncthreads();

  constexpr float DT6 = DT / 6.f;
#pragma unroll
  for (int i = 0; i < 8; ++i) {
    const int chunk = tid + i * 256;          // 2048 chunks of 8 elems
    const int row = chunk >> 4;
    const int cc = chunk & 15;
    const int col0 = bn0 + cc * 8;
    const us8 kv8 = *(const us8*)&C[row * 136 + cc * 8];
    const size_t gidx = (size_t)(bm0 + row) * NCOL + col0;

    if (MODE == 0) {
      *(us8*)&out0[gidx] = kv8;
    } else if (MODE == 1) {
      const f32x8 b = *(const f32x8*)&bias[col0];
      us8 o1;
#pragma unroll
      for (int e = 0; e < 8; ++e) o1[e] = f2bf(fast_tanh(b2f(kv8[e]) + b[e]));
      *(us8*)&out0[gidx] = kv8;
      *(us8*)&out1[gidx] = o1;
    } else if (MODE == 2) {
      const f32x8 b = *(const f32x8*)&bias[col0];
      float x2[8]; us8 o0;
#pragma unroll
      for (int e = 0; e < 8; ++e) { x2[e] = fast_tanh(b2f(kv8[e]) + b[e]); o0[e] = f2bf(x2[e]); }
      *(us8*)&out0[gidx] = o0;
      if (flag) {
        *(us8*)&out1[gidx] = o0;
      } else {
        const us8 xt = *(const us8*)&out1[gidx];
        us8 nxt;
#pragma unroll
        for (int e = 0; e < 8; ++e) nxt[e] = f2bf(b2f(xt[e]) + p0 * x2[e]);
        *(us8*)&out1[gidx] = nxt;
      }
    } else if (MODE == 3) {
      const f32x8 b  = *(const f32x8*)&bias[col0];
      const f32x8 wv = *(const f32x8*)&wl[col0];
      const f32x8 cv = *(const f32x8*)&c31[col0];
      const us8 hw = *(const us8*)&auxR1[gidx];
      us8 o0, gs;
      if (flag) {
#pragma unroll
        for (int e = 0; e < 8; ++e) {
          const float g = b2f(kv8[e]);
          gs[e] = f2bf(g);
          o0[e] = f2bf(fast_tanh(b2f(hw[e]) + p1 * (g + cv[e]) + b[e] + p2 * wv[e]));
        }
      } else {
        const us8 og = *(const us8*)&out1[gidx];
#pragma unroll
        for (int e = 0; e < 8; ++e) {
          const float g = b2f(kv8[e]);
          gs[e] = f2bf(b2f(og[e]) + p0 * g);
          o0[e] = f2bf(fast_tanh(b2f(hw[e]) + p1 * (g + cv[e]) + b[e] + p2 * wv[e]));
        }
      }
      *(us8*)&out1[gidx] = gs;
      *(us8*)&out0[gidx] = o0;
    } else if (MODE == 4) {
      const f32x8 b  = *(const f32x8*)&bias[col0];
      const f32x8 wv = *(const f32x8*)&wl[col0];
      const f32x8 cv = *(const f32x8*)&c31[col0];
      const us8 hw = *(const us8*)&auxR1[gidx];
      const us8 gs = *(const us8*)&auxR2[gidx];
      us8 o0, o1;
#pragma unroll
      for (int e = 0; e < 8; ++e) {
        const float hn = b2f(hw[e]) + DT6 * (b2f(gs[e]) + b2f(kv8[e])) + DT * cv[e];
        o1[e] = f2bf(hn);
        o0[e] = f2bf(fast_tanh(hn + b[e] + p2 * wv[e]));
      }
      *(us8*)&out1[gidx] = o1;
      *(us8*)&out0[gidx] = o0;
    } else {  // MODE 5
      const f32x8 b  = *(const f32x8*)&bias[col0];
      const f32x8 h8 = *(const f32x8*)&h0f[gidx];
      f32x8 o;
#pragma unroll
      for (int e = 0; e < 8; ++e) o[e] = h8[e] + DT6 * b2f(kv8[e]) + b[e];
      *(f32x8*)&outf[gidx] = o;
    }
  }
}

extern "C" void kernel_launch(void* const* d_in, const int* in_sizes, int n_in,
                              void* d_out, int out_size, void* d_ws, size_t ws_size,
                              hipStream_t stream) {
  (void)in_sizes; (void)n_in; (void)out_size; (void)ws_size;
  const float* h_in = (const float*)d_in[0];
  const float* W1   = (const float*)d_in[1];   // 1025 x 1024
  const float* b1   = (const float*)d_in[2];
  const float* W2   = (const float*)d_in[3];
  const float* b2   = (const float*)d_in[4];
  const float* W3   = (const float*)d_in[5];
  const float* b3   = (const float*)d_in[6];
  const float* W1last = W1 + (size_t)1024 * 1024;

  char* ws = (char*)d_ws;
  ushort_t* W1t  = (ushort_t*)(ws);                   // 2 MiB (reused for W3^T at end)
  ushort_t* W2t  = (ushort_t*)(ws + (2ull << 20));    // 2 MiB
  ushort_t* Bt31 = (ushort_t*)(ws + (4ull << 20));    // 2 MiB (W31^T, i.e. GEMM Bt form)
  float*    c31  = (float*)   (ws + (6ull << 20));    // 4 KiB
  ushort_t* hW1b = (ushort_t*)(ws + (8ull << 20));    // 16 MiB bf16 h@W1
  ushort_t* x1   = (ushort_t*)(ws + (24ull << 20));   // 16 MiB
  ushort_t* x2   = (ushort_t*)(ws + (40ull << 20));   // 16 MiB (hb at start)
  ushort_t* XT   = (ushort_t*)(ws + (56ull << 20));   // 16 MiB (W3b at start)
  ushort_t* GS   = (ushort_t*)d_out;                  // 16 MiB in d_out low half (dead before final)
  float*    OUT  = (float*)d_out;

  const float dt = 0.1f;
  constexpr int GRID = 512, BLK = 256;
  dim3 tb(32, 8), tg(32, 32);

  // ---- precompute ----
  transpose_bf16<<<tg, tb, 0, stream>>>(W1, W1t);
  transpose_bf16<<<tg, tb, 0, stream>>>(W2, W2t);
  conv_bf16<<<1024, 256, 0, stream>>>(W3, XT);        // W3b (transient in XT slot)
  conv_bf16<<<8192, 256, 0, stream>>>(h_in, x2);      // hb  (transient in x2 slot)
  c31_kernel<<<4, 256, 0, stream>>>(W1t, b3, c31);
  // Bt31[n][m] = sum_j W1a[j][n] * W3[m][j]  ->  gemm(A=W1t, Bt=W3b)
  gemm_fused<0><<<64, BLK, 0, stream>>>(W1t, XT, nullptr, nullptr, nullptr, nullptr, nullptr,
                                        Bt31, nullptr, 0.f, 0.f, 0.f, 0, nullptr, nullptr);
  // hW1 = h0@W1a ; x1_1 = tanh(hW1 + b1)  (t=0)
  gemm_fused<1><<<GRID, BLK, 0, stream>>>(x2, W1t, b1, nullptr, nullptr, nullptr, nullptr,
                                          hW1b, x1, 0.f, 0.f, 0.f, 0, nullptr, nullptr);

  for (int step = 0; step < 10; ++step) {
    const float t0 = step * dt;
    // stage 1
    gemm_fused<2><<<GRID, BLK, 0, stream>>>(x1, W2t, b2, nullptr, nullptr, nullptr, nullptr,
                                            x2, XT, 1.f, 0.f, 0.f, (step == 0), nullptr, nullptr);
    gemm_fused<3><<<GRID, BLK, 0, stream>>>(x2, Bt31, b1, W1last, c31, hW1b, nullptr,
                                            x1, GS, 1.f, 0.5f * dt, t0 + 0.5f * dt, 1, nullptr, nullptr);
    // stage 2
    gemm_fused<2><<<GRID, BLK, 0, stream>>>(x1, W2t, b2, nullptr, nullptr, nullptr, nullptr,
                                            x2, XT, 2.f, 0.f, 0.f, 0, nullptr, nullptr);
    gemm_fused<3><<<GRID, BLK, 0, stream>>>(x2, Bt31, b1, W1last, c31, hW1b, nullptr,
                                            x1, GS, 2.f, 0.5f * dt, t0 + 0.5f * dt, 0, nullptr, nullptr);
    // stage 3
    gemm_fused<2><<<GRID, BLK, 0, stream>>>(x1, W2t, b2, nullptr, nullptr, nullptr, nullptr,
                                            x2, XT, 2.f, 0.f, 0.f, 0, nullptr, nullptr);
    gemm_fused<3><<<GRID, BLK, 0, stream>>>(x2, Bt31, b1, W1last, c31, hW1b, nullptr,
                                            x1, GS, 2.f, dt, t0 + dt, 0, nullptr, nullptr);
    // stage 4
    gemm_fused<2><<<GRID, BLK, 0, stream>>>(x1, W2t, b2, nullptr, nullptr, nullptr, nullptr,
                                            x2, XT, 1.f, 0.f, 0.f, 0, nullptr, nullptr);
    if (step < 9) {
      // hW1' = hW1 + dt/6*(GS + g4) + dt*c31 ; x1_next = tanh(hW1' + b1 + t_next*w1l)
      gemm_fused<4><<<GRID, BLK, 0, stream>>>(x2, Bt31, b1, W1last, c31, hW1b, GS,
                                              x1, hW1b, 0.f, 0.f, t0 + dt, 0, nullptr, nullptr);
    }
  }

  // final: h = h0 + dt/6 * XT@W3 + b3   (sum of dt*b3 over 10 steps = b3)
  transpose_bf16<<<tg, tb, 0, stream>>>(W3, W1t);     // W3^T into dead W1t slot
  gemm_fused<5><<<GRID, BLK, 0, stream>>>(XT, W1t, b3, nullptr, nullptr, nullptr, nullptr,
                                          nullptr, nullptr, 0.f, 0.f, 0.f, 0, h_in, OUT);
}

// Round 7
// 1702.742 us; speedup vs baseline: 2.0248x; 1.2982x over previous
//
#include <hip/hip_runtime.h>

// NeuralODE RK4, restructured (R6 algebra: W31=W3@W1a merged GEMM, hW1 state,
// XT deferred reconstruction) + MX-fp8 GEMM core for the 79 inner GEMMs:
// mfma_scale_f32_32x32x64_f8f6f4 (2x bf16 rate, halves LDS bytes/FLOP which
// was the measured plateau), weights stored x32 in e4m3 with HW MX scale 2^-5,
// activations e4m3 scale 1. Initial/final GEMMs stay bf16 (h not tanh-bounded).

typedef __attribute__((ext_vector_type(8))) __bf16 bf16x8;
typedef __attribute__((ext_vector_type(4))) float f32x4;
typedef __attribute__((ext_vector_type(8))) float f32x8;
typedef __attribute__((ext_vector_type(16))) float f32x16;
typedef __attribute__((ext_vector_type(8))) unsigned short us8;
typedef __attribute__((ext_vector_type(4))) int i32x4;
typedef __attribute__((ext_vector_type(8))) int i32x8;
typedef unsigned short ushort_t;
typedef unsigned char u8;

#define SCALE_ONE  0x7F7F7F7Fu   // E8M0 1.0 per byte
#define SCALE_INV32 0x7A7A7A7Au  // E8M0 2^-5 per byte

#define GLOAD16(gp, lp) \
  __builtin_amdgcn_global_load_lds((const __attribute__((address_space(1))) unsigned int*)(gp), \
                                   (__attribute__((address_space(3))) unsigned int*)(lp), 16, 0, 0)

__device__ __forceinline__ ushort_t f2bf(float f) {
  union { float f; unsigned u; } v; v.f = f;
  unsigned r = v.u + 0x7fffu + ((v.u >> 16) & 1u);
  return (ushort_t)(r >> 16);
}
__device__ __forceinline__ float b2f(ushort_t u) {
  union { unsigned u; float f; } v; v.u = ((unsigned)u) << 16; return v.f;
}
__device__ __forceinline__ float fast_tanh(float x) {
  float e = __expf(2.0f * x);
  return 1.0f - 2.0f * __builtin_amdgcn_rcpf(e + 1.0f);
}
__device__ __forceinline__ uint2 pack_fp8x8(const float* v) {
  int a = __builtin_amdgcn_cvt_pk_fp8_f32(v[0], v[1], 0, false);
  a = __builtin_amdgcn_cvt_pk_fp8_f32(v[2], v[3], a, true);
  int b = __builtin_amdgcn_cvt_pk_fp8_f32(v[4], v[5], 0, false);
  b = __builtin_amdgcn_cvt_pk_fp8_f32(v[6], v[7], b, true);
  return make_uint2((unsigned)a, (unsigned)b);
}

// ---------------- weight transpose (K x N fp32 -> N x K bf16) ----------------
__global__ void transpose_bf16(const float* __restrict__ in, ushort_t* __restrict__ out) {
  __shared__ float tile[32][33];
  const int bx = blockIdx.x * 32, by = blockIdx.y * 32;
  const int tx = threadIdx.x, ty = threadIdx.y;
#pragma unroll
  for (int i = 0; i < 32; i += 8)
    tile[ty + i][tx] = in[(size_t)(by + ty + i) * 1024 + bx + tx];
  __syncthreads();
#pragma unroll
  for (int i = 0; i < 32; i += 8)
    out[(size_t)(bx + ty + i) * 1024 + by + tx] = f2bf(tile[tx][ty + i]);
}

// ------------- weight transpose -> fp8 x32 (K x N fp32 -> N x K e4m3) -------
__global__ void transpose_fp8(const float* __restrict__ in, u8* __restrict__ out) {
  __shared__ float tile[32][33];
  const int bx = blockIdx.x * 32, by = blockIdx.y * 32;
  const int tx = threadIdx.x, ty = threadIdx.y;
#pragma unroll
  for (int i = 0; i < 32; i += 8)
    tile[ty + i][tx] = in[(size_t)(by + ty + i) * 1024 + bx + tx];
  __syncthreads();
#pragma unroll
  for (int i = 0; i < 32; i += 8) {
    const float v = 32.f * tile[tx][ty + i];
    int r = __builtin_amdgcn_cvt_pk_fp8_f32(v, v, 0, false);
    out[(size_t)(bx + ty + i) * 1024 + by + tx] = (u8)(r & 0xFF);
  }
}

// ---------------- fp32 -> bf16 convert ----------------
__global__ void conv_bf16(const float* __restrict__ in, ushort_t* __restrict__ out) {
  size_t i = ((size_t)blockIdx.x * 256 + threadIdx.x) * 4;
  float4 v = *(const float4*)&in[i];
  ushort4 o;
  o.x = f2bf(v.x); o.y = f2bf(v.y); o.z = f2bf(v.z); o.w = f2bf(v.w);
  *(ushort4*)&out[i] = o;
}

// ---------------- c31 = b3 @ W1a ----------------
__global__ void c31_kernel(const ushort_t* __restrict__ W1t, const float* __restrict__ b3,
                           float* __restrict__ c31) {
  const int j = blockIdx.x * 256 + threadIdx.x;
  float acc = 0.f;
  for (int c = 0; c < 128; ++c) {
    const us8 w = *(const us8*)&W1t[(size_t)j * 1024 + c * 8];
    const f32x8 b = *(const f32x8*)&b3[c * 8];
#pragma unroll
    for (int e = 0; e < 8; ++e) acc += b2f(w[e]) * b[e];
  }
  c31[j] = acc;
}

// =================== bf16 GEMM (modes 0,1,5) — proven R6 core ===================
// MODE 0: out8 = fp8(32*C)            (Bt31 precompute)
// MODE 1: outb = bf16(C) [hW1]; out8 = fp8(tanh(C + bias)) [x1 @ t=0]
// MODE 5: outf = h0f + DT/6*C + bias  (final fp32 h)
template<int MODE>
__global__ void __launch_bounds__(256, 2)
gemm_bf16(const ushort_t* __restrict__ Ag, const ushort_t* __restrict__ Bg,
          const float* __restrict__ bias,
          ushort_t* __restrict__ outb, u8* __restrict__ out8,
          const float* __restrict__ h0f, float* __restrict__ outf)
{
  constexpr int K = 1024, NCOL = 1024, NT = 16;
  constexpr float DT = 0.1f;
  __shared__ __align__(16) ushort_t lds[2][16384];

  const int bid = blockIdx.x;
  const int nb = (int)gridDim.x >> 3;
  const int logical = (bid & 7) * nb + (bid >> 3);
  const int bm0 = (logical >> 3) * 128;
  const int bn0 = (logical & 7) * 128;

  const int tid = threadIdx.x;
  const int w = tid >> 6, l = tid & 63;
  const int wr = w >> 1, wc = w & 1;

  const int srow = l >> 3;
  const int sclog = (l & 7) ^ srow;
  const size_t gA0 = (size_t)(bm0 + w * 32 + srow) * K + sclog * 8;
  const size_t gB0 = (size_t)(bn0 + w * 32 + srow) * K + sclog * 8;
  const int ldsAo = w * 2048 + l * 8;
  const int ldsBo = 8192 + w * 2048 + l * 8;

#define STAGEB(s, t1) do { \
    const ushort_t* ga = Ag + gA0 + (size_t)(t1) * 64; \
    const ushort_t* gb = Bg + gB0 + (size_t)(t1) * 64; \
    GLOAD16(ga,          &lds[s][ldsAo]); \
    GLOAD16(ga + 8 * K,  &lds[s][ldsAo + 512]); \
    GLOAD16(ga + 16 * K, &lds[s][ldsAo + 1024]); \
    GLOAD16(ga + 24 * K, &lds[s][ldsAo + 1536]); \
    GLOAD16(gb,          &lds[s][ldsBo]); \
    GLOAD16(gb + 8 * K,  &lds[s][ldsBo + 512]); \
    GLOAD16(gb + 16 * K, &lds[s][ldsBo + 1024]); \
    GLOAD16(gb + 24 * K, &lds[s][ldsBo + 1536]); } while (0)

  const int r = l & 15, kb = l >> 4, xr = r & 7;
  const int aRow = (wr * 64 + r) * 64;
  const int bRow = 8192 + (wc * 64 + r) * 64;
  const int c0 = ((0 | kb) ^ xr) * 8;
  const int c1 = ((4 | kb) ^ xr) * 8;

  f32x4 acc[4][4];
#pragma unroll
  for (int m = 0; m < 4; ++m)
#pragma unroll
    for (int n = 0; n < 4; ++n) acc[m][n] = (f32x4){0.f, 0.f, 0.f, 0.f};

  STAGEB(0, 0);

  for (int t = 0; t < NT; ++t) {
    const int cur = t & 1;
    __builtin_amdgcn_s_barrier();
    if (t + 1 < NT) {
      STAGEB(cur ^ 1, t + 1);
      asm volatile("s_waitcnt vmcnt(8)" ::: "memory");
    } else {
      asm volatile("s_waitcnt vmcnt(0)" ::: "memory");
    }
    __builtin_amdgcn_s_barrier();
    __builtin_amdgcn_sched_barrier(0);

    const ushort_t* Lb = &lds[cur][0];
    bf16x8 av[4], bv[4];
#pragma unroll
    for (int m = 0; m < 4; ++m) av[m] = *(const bf16x8*)(Lb + aRow + m * 1024 + c0);
#pragma unroll
    for (int n = 0; n < 4; ++n) bv[n] = *(const bf16x8*)(Lb + bRow + n * 1024 + c0);
    __builtin_amdgcn_s_setprio(1);
#pragma unroll
    for (int m = 0; m < 4; ++m)
#pragma unroll
      for (int n = 0; n < 4; ++n)
        acc[m][n] = __builtin_amdgcn_mfma_f32_16x16x32_bf16(av[m], bv[n], acc[m][n], 0, 0, 0);
    __builtin_amdgcn_s_setprio(0);
#pragma unroll
    for (int m = 0; m < 4; ++m) av[m] = *(const bf16x8*)(Lb + aRow + m * 1024 + c1);
#pragma unroll
    for (int n = 0; n < 4; ++n) bv[n] = *(const bf16x8*)(Lb + bRow + n * 1024 + c1);
    __builtin_amdgcn_s_setprio(1);
#pragma unroll
    for (int m = 0; m < 4; ++m)
#pragma unroll
      for (int n = 0; n < 4; ++n)
        acc[m][n] = __builtin_amdgcn_mfma_f32_16x16x32_bf16(av[m], bv[n], acc[m][n], 0, 0, 0);
    __builtin_amdgcn_s_setprio(0);
  }
#undef STAGEB

  __syncthreads();
  ushort_t* C = &lds[0][0];
  const int er = (l >> 4) * 4;
  const int ec = l & 15;
#pragma unroll
  for (int n = 0; n < 4; ++n) {
    const int lc = wc * 64 + n * 16 + ec;
#pragma unroll
    for (int m = 0; m < 4; ++m) {
#pragma unroll
      for (int j = 0; j < 4; ++j) {
        const int lr = wr * 64 + m * 16 + er + j;
        C[lr * 136 + lc] = f2bf(acc[m][n][j]);
      }
    }
  }
  __syncthreads();

  constexpr float DT6 = DT / 6.f;
#pragma unroll
  for (int i = 0; i < 8; ++i) {
    const int chunk = tid + i * 256;
    const int row = chunk >> 4;
    const int cc = chunk & 15;
    const int col0 = bn0 + cc * 8;
    const us8 kv8 = *(const us8*)&C[row * 136 + cc * 8];
    const size_t gidx = (size_t)(bm0 + row) * NCOL + col0;

    if (MODE == 0) {
      float v[8];
#pragma unroll
      for (int e = 0; e < 8; ++e) v[e] = 32.f * b2f(kv8[e]);
      *(uint2*)&out8[gidx] = pack_fp8x8(v);
    } else if (MODE == 1) {
      const f32x8 b = *(const f32x8*)&bias[col0];
      float v[8];
#pragma unroll
      for (int e = 0; e < 8; ++e) v[e] = fast_tanh(b2f(kv8[e]) + b[e]);
      *(us8*)&outb[gidx] = kv8;                 // hW1 (bf16)
      *(uint2*)&out8[gidx] = pack_fp8x8(v);     // x1 (fp8)
    } else {  // MODE 5
      const f32x8 b = *(const f32x8*)&bias[col0];
      const f32x8 h8 = *(const f32x8*)&h0f[gidx];
      f32x8 o;
#pragma unroll
      for (int e = 0; e < 8; ++e) o[e] = h8[e] + DT6 * b2f(kv8[e]) + b[e];
      *(f32x8*)&outf[gidx] = o;
    }
  }
}

// =================== MX-fp8 GEMM (modes 2,3,4) ===================
// C[i][j] = sum_k A[i][k]*Bt[j][k]*2^-5 via mfma_scale (B stored x32).
// MODE 2: x2 = tanh(C+b); out8=fp8(x2); XT(bfio) = flag ? x2 : XT + p0*x2
// MODE 3: g = C; GS(bfio) = flag ? g : GS + p0*g;
//         out8 = fp8(tanh(hW1 + p1*(g + c31) + b + p2*wl))
// MODE 4: hn = hW1 + DT/6*(GS + C) + DT*c31; hW1w = bf16(hn);
//         out8 = fp8(tanh(hn + b + p2*wl))
template<int MODE>
__global__ void __launch_bounds__(256, 2)
gemm_fp8(const u8* __restrict__ Ag, const u8* __restrict__ Bg,
         const float* __restrict__ bias, const float* __restrict__ wl,
         const float* __restrict__ c31,
         const ushort_t* __restrict__ hW1r, const ushort_t* __restrict__ GSr,
         u8* __restrict__ out8, ushort_t* __restrict__ bfio, ushort_t* __restrict__ hW1w,
         float p0, float p1, float p2, int flag)
{
  constexpr int NT = 16;  // BK = 64 fp8 bytes
  constexpr float DT = 0.1f, DT6 = DT / 6.f;
  __shared__ __align__(16) u8 bufs[2][16384];         // A 8KB | B 8KB per buffer
  __shared__ __align__(16) ushort_t Cst[128 * 136];

  const int bid = blockIdx.x;
  const int nb = (int)gridDim.x >> 3;
  const int logical = (bid & 7) * nb + (bid >> 3);
  const int bm0 = (logical >> 3) * 128;
  const int bn0 = (logical & 7) * 128;

  const int tid = threadIdx.x;
  const int w = tid >> 6, l = tid & 63;
  const int wr = w >> 1, wc = w & 1;                  // wave tile 64x64
  const int l31 = l & 31, kg = l >> 5;

  // ---- staging: slot s(16B) at LDS s*16; source (r,kc): rp=s>>3, p=s&7,
  //      q=p^(rp&7), r=2rp+(q>>2), kc=q&3. 2 insts A + 2 insts B per tile.
  auto srcoff = [](int slot) -> int {
    int rp = slot >> 3, p = slot & 7, q = p ^ (rp & 7);
    return (2 * rp + (q >> 2)) * 1024 + (q & 3) * 16;
  };
  const int so0 = srcoff(tid), so1 = srcoff(256 + tid);
  const u8* gA = Ag + (size_t)bm0 * 1024;
  const u8* gB = Bg + (size_t)bn0 * 1024;
  const int ld0 = tid * 16, ld1 = 4096 + tid * 16;

#define STAGEF(s, t1) do { \
    GLOAD16(gA + so0 + (t1) * 64, &bufs[s][ld0]); \
    GLOAD16(gA + so1 + (t1) * 64, &bufs[s][ld1]); \
    GLOAD16(gB + so0 + (t1) * 64, &bufs[s][8192 + ld0]); \
    GLOAD16(gB + so1 + (t1) * 64, &bufs[s][8192 + ld1]); } while (0)

  // ---- fragment addresses: lane reads 32B (k = kg*32..+32) of row r ----
  auto ldsAddr = [](int r2, int kc) -> int {
    int q = ((r2 & 1) << 2) | kc; int p = q ^ ((r2 >> 1) & 7);
    return (r2 >> 1) * 128 + p * 16;
  };
  const int kc2 = kg * 2;
  const int ra0 = wr * 64 + l31, ra1 = ra0 + 32;
  const int rb0 = wc * 64 + l31, rb1 = rb0 + 32;
  const int aA00 = ldsAddr(ra0, kc2), aA01 = ldsAddr(ra0, kc2 + 1);
  const int aA10 = ldsAddr(ra1, kc2), aA11 = ldsAddr(ra1, kc2 + 1);
  const int bA00 = 8192 + ldsAddr(rb0, kc2), bA01 = 8192 + ldsAddr(rb0, kc2 + 1);
  const int bA10 = 8192 + ldsAddr(rb1, kc2), bA11 = 8192 + ldsAddr(rb1, kc2 + 1);

  f32x16 acc00, acc01, acc10, acc11;
#pragma unroll
  for (int i = 0; i < 16; ++i) { acc00[i] = 0.f; acc01[i] = 0.f; acc10[i] = 0.f; acc11[i] = 0.f; }

#define LD8(dst, o0, o1) do { \
    i32x4 lo_ = *(const i32x4*)(Lb + (o0)); \
    i32x4 hi_ = *(const i32x4*)(Lb + (o1)); \
    dst = (i32x8){lo_[0], lo_[1], lo_[2], lo_[3], hi_[0], hi_[1], hi_[2], hi_[3]}; } while (0)

  STAGEF(0, 0);

  for (int t = 0; t < NT; ++t) {
    const int cur = t & 1;
    __builtin_amdgcn_s_barrier();
    if (t + 1 < NT) {
      STAGEF(cur ^ 1, t + 1);
      asm volatile("s_waitcnt vmcnt(4)" ::: "memory");
    } else {
      asm volatile("s_waitcnt vmcnt(0)" ::: "memory");
    }
    __builtin_amdgcn_s_barrier();
    __builtin_amdgcn_sched_barrier(0);

    const u8* Lb = &bufs[cur][0];
    i32x8 a0, a1, b0, b1;
    LD8(a0, aA00, aA01);
    LD8(a1, aA10, aA11);
    LD8(b0, bA00, bA01);
    LD8(b1, bA10, bA11);
    __builtin_amdgcn_s_setprio(1);
    acc00 = __builtin_amdgcn_mfma_scale_f32_32x32x64_f8f6f4(a0, b0, acc00, 0, 0, 0, SCALE_ONE, 0, SCALE_INV32);
    acc01 = __builtin_amdgcn_mfma_scale_f32_32x32x64_f8f6f4(a0, b1, acc01, 0, 0, 0, SCALE_ONE, 0, SCALE_INV32);
    acc10 = __builtin_amdgcn_mfma_scale_f32_32x32x64_f8f6f4(a1, b0, acc10, 0, 0, 0, SCALE_ONE, 0, SCALE_INV32);
    acc11 = __builtin_amdgcn_mfma_scale_f32_32x32x64_f8f6f4(a1, b1, acc11, 0, 0, 0, SCALE_ONE, 0, SCALE_INV32);
    __builtin_amdgcn_s_setprio(0);
  }
#undef STAGEF

  // ---- epilogue: stage raw bf16(C); 32x32 C/D layout:
  //      col = lane&31, row = (reg&3)+8*(reg>>2)+4*(lane>>5)
#define STORE_ACC(A_, mm, nn) do { \
    _Pragma("unroll") \
    for (int reg = 0; reg < 16; ++reg) { \
      const int lrow = wr * 64 + (mm) * 32 + (reg & 3) + 8 * (reg >> 2) + 4 * kg; \
      const int lcol = wc * 64 + (nn) * 32 + l31; \
      Cst[lrow * 136 + lcol] = f2bf(A_[reg]); } } while (0)
  STORE_ACC(acc00, 0, 0);
  STORE_ACC(acc01, 0, 1);
  STORE_ACC(acc10, 1, 0);
  STORE_ACC(acc11, 1, 1);
#undef STORE_ACC
  __syncthreads();

#pragma unroll
  for (int i = 0; i < 8; ++i) {
    const int chunk = tid + i * 256;
    const int row = chunk >> 4;
    const int cc = chunk & 15;
    const int col0 = bn0 + cc * 8;
    const us8 kv8 = *(const us8*)&Cst[row * 136 + cc * 8];
    const size_t gidx = (size_t)(bm0 + row) * 1024 + col0;

    if (MODE == 2) {
      const f32x8 b = *(const f32x8*)&bias[col0];
      float x2v[8];
#pragma unroll
      for (int e = 0; e < 8; ++e) x2v[e] = fast_tanh(b2f(kv8[e]) + b[e]);
      *(uint2*)&out8[gidx] = pack_fp8x8(x2v);
      if (flag) {
        us8 nx;
#pragma unroll
        for (int e = 0; e < 8; ++e) nx[e] = f2bf(x2v[e]);
        *(us8*)&bfio[gidx] = nx;
      } else {
        const us8 xt = *(const us8*)&bfio[gidx];
        us8 nx;
#pragma unroll
        for (int e = 0; e < 8; ++e) nx[e] = f2bf(b2f(xt[e]) + p0 * x2v[e]);
        *(us8*)&bfio[gidx] = nx;
      }
    } else if (MODE == 3) {
      const f32x8 b  = *(const f32x8*)&bias[col0];
      const f32x8 wv = *(const f32x8*)&wl[col0];
      const f32x8 cv = *(const f32x8*)&c31[col0];
      const us8 hw = *(const us8*)&hW1r[gidx];
      float x1v[8]; us8 gs;
      if (flag) {
#pragma unroll
        for (int e = 0; e < 8; ++e) {
          const float g = b2f(kv8[e]);
          gs[e] = f2bf(g);
          x1v[e] = fast_tanh(b2f(hw[e]) + p1 * (g + cv[e]) + b[e] + p2 * wv[e]);
        }
      } else {
        const us8 og = *(const us8*)&bfio[gidx];
#pragma unroll
        for (int e = 0; e < 8; ++e) {
          const float g = b2f(kv8[e]);
          gs[e] = f2bf(b2f(og[e]) + p0 * g);
          x1v[e] = fast_tanh(b2f(hw[e]) + p1 * (g + cv[e]) + b[e] + p2 * wv[e]);
        }
      }
      *(us8*)&bfio[gidx] = gs;
      *(uint2*)&out8[gidx] = pack_fp8x8(x1v);
    } else {  // MODE 4
      const f32x8 b  = *(const f32x8*)&bias[col0];
      const f32x8 wv = *(const f32x8*)&wl[col0];
      const f32x8 cv = *(const f32x8*)&c31[col0];
      const us8 hw = *(const us8*)&hW1r[gidx];
      const us8 gs = *(const us8*)&GSr[gidx];
      float x1v[8]; us8 o1;
#pragma unroll
      for (int e = 0; e < 8; ++e) {
        const float hn = b2f(hw[e]) + DT6 * (b2f(gs[e]) + b2f(kv8[e])) + DT * cv[e];
        o1[e] = f2bf(hn);
        x1v[e] = fast_tanh(hn + b[e] + p2 * wv[e]);
      }
      *(us8*)&hW1w[gidx] = o1;
      *(uint2*)&out8[gidx] = pack_fp8x8(x1v);
    }
  }
}

extern "C" void kernel_launch(void* const* d_in, const int* in_sizes, int n_in,
                              void* d_out, int out_size, void* d_ws, size_t ws_size,
                              hipStream_t stream) {
  (void)in_sizes; (void)n_in; (void)out_size; (void)ws_size;
  const float* h_in = (const float*)d_in[0];
  const float* W1   = (const float*)d_in[1];   // 1025 x 1024
  const float* b1   = (const float*)d_in[2];
  const float* W2   = (const float*)d_in[3];
  const float* b2   = (const float*)d_in[4];
  const float* W3   = (const float*)d_in[5];
  const float* b3   = (const float*)d_in[6];
  const float* W1last = W1 + (size_t)1024 * 1024;

  char* ws = (char*)d_ws;
  ushort_t* W1t   = (ushort_t*)(ws);                   // 2 MiB (reused for W3^T at end)
  u8*       W2t8  = (u8*)      (ws + (2ull << 20));    // 1 MiB fp8 x32
  u8*       Bt318 = (u8*)      (ws + (3ull << 20));    // 1 MiB fp8 x32
  float*    c31   = (float*)   (ws + (4ull << 20));    // 4 KiB
  ushort_t* hW1b  = (ushort_t*)(ws + (8ull << 20));    // 16 MiB bf16
  u8*       x1    = (u8*)      (ws + (24ull << 20));   // 8 MiB fp8
  u8*       x2    = (u8*)      (ws + (32ull << 20));   // 8 MiB fp8
  ushort_t* XT    = (ushort_t*)(ws + (40ull << 20));   // 16 MiB bf16 (W3b transient)
  ushort_t* GS    = (ushort_t*)d_out;                  // bf16, d_out low half (hb transient)
  ushort_t* hb    = (ushort_t*)d_out;                  // bf16 h (dead after MODE1)
  float*    OUT   = (float*)d_out;

  const float dt = 0.1f;
  constexpr int GRID = 512, BLK = 256;
  dim3 tb(32, 8), tg(32, 32);

  // ---- precompute ----
  transpose_bf16<<<tg, tb, 0, stream>>>(W1, W1t);
  transpose_fp8 <<<tg, tb, 0, stream>>>(W2, W2t8);
  conv_bf16<<<1024, 256, 0, stream>>>(W3, XT);         // W3b transient in XT slot
  conv_bf16<<<8192, 256, 0, stream>>>(h_in, hb);
  c31_kernel<<<4, 256, 0, stream>>>(W1t, b3, c31);
  // Bt31 = (W1t @ W3b^T): [m][n] = W31[n][m]  -> fp8 x32
  gemm_bf16<0><<<64, BLK, 0, stream>>>(W1t, XT, nullptr, nullptr, Bt318, nullptr, nullptr);
  // hW1 = h0@W1a (bf16); x1 = fp8(tanh(hW1 + b1))   (t = 0)
  gemm_bf16<1><<<GRID, BLK, 0, stream>>>(hb, W1t, b1, hW1b, x1, nullptr, nullptr);

  for (int step = 0; step < 10; ++step) {
    const float t0 = step * dt;
    // stage 1
    gemm_fp8<2><<<GRID, BLK, 0, stream>>>(x1, W2t8, b2, nullptr, nullptr, nullptr, nullptr,
                                          x2, XT, nullptr, 1.f, 0.f, 0.f, (step == 0));
    gemm_fp8<3><<<GRID, BLK, 0, stream>>>(x2, Bt318, b1, W1last, c31, hW1b, nullptr,
                                          x1, GS, nullptr, 1.f, 0.5f * dt, t0 + 0.5f * dt, 1);
    // stage 2
    gemm_fp8<2><<<GRID, BLK, 0, stream>>>(x1, W2t8, b2, nullptr, nullptr, nullptr, nullptr,
                                          x2, XT, nullptr, 2.f, 0.f, 0.f, 0);
    gemm_fp8<3><<<GRID, BLK, 0, stream>>>(x2, Bt318, b1, W1last, c31, hW1b, nullptr,
                                          x1, GS, nullptr, 2.f, 0.5f * dt, t0 + 0.5f * dt, 0);
    // stage 3
    gemm_fp8<2><<<GRID, BLK, 0, stream>>>(x1, W2t8, b2, nullptr, nullptr, nullptr, nullptr,
                                          x2, XT, nullptr, 2.f, 0.f, 0.f, 0);
    gemm_fp8<3><<<GRID, BLK, 0, stream>>>(x2, Bt318, b1, W1last, c31, hW1b, nullptr,
                                          x1, GS, nullptr, 2.f, dt, t0 + dt, 0);
    // stage 4
    gemm_fp8<2><<<GRID, BLK, 0, stream>>>(x1, W2t8, b2, nullptr, nullptr, nullptr, nullptr,
                                          x2, XT, nullptr, 1.f, 0.f, 0.f, 0);
    if (step < 9) {
      gemm_fp8<4><<<GRID, BLK, 0, stream>>>(x2, Bt318, b1, W1last, c31, hW1b, GS,
                                            x1, nullptr, hW1b, 0.f, 0.f, t0 + dt, 0);
    }
  }

  // final: h = h0 + dt/6 * XT@W3 + b3
  transpose_bf16<<<tg, tb, 0, stream>>>(W3, W1t);      // W3^T into dead W1t slot
  gemm_bf16<5><<<GRID, BLK, 0, stream>>>(XT, W1t, b3, nullptr, nullptr, h_in, OUT);
}

// Round 8
// 1586.000 us; speedup vs baseline: 2.1738x; 1.0736x over previous
//
#include <hip/hip_runtime.h>

// NeuralODE RK4, restructured algebra (W31 merged GEMM, hW1 state, XT deferred
// reconstruction) + MX-fp8 GEMM core. R8: epilogue HBM-traffic cuts —
// (1) MODE2 writes x2 stage buffers only (XT fold moved to MODE4 epilogue,
//     reading fp8 x2 buffers: -64MB/step), step 9 folded by tiny kernel;
// (2) hW1/GS state reads hoisted before the C-staging barrier (overlap).

typedef __attribute__((ext_vector_type(8))) __bf16 bf16x8;
typedef __attribute__((ext_vector_type(4))) float f32x4;
typedef __attribute__((ext_vector_type(8))) float f32x8;
typedef __attribute__((ext_vector_type(16))) float f32x16;
typedef __attribute__((ext_vector_type(8))) unsigned short us8;
typedef __attribute__((ext_vector_type(4))) int i32x4;
typedef __attribute__((ext_vector_type(8))) int i32x8;
typedef unsigned short ushort_t;
typedef unsigned char u8;

#define SCALE_ONE  0x7F7F7F7Fu   // E8M0 1.0 per byte
#define SCALE_INV32 0x7A7A7A7Au  // E8M0 2^-5 per byte

#define GLOAD16(gp, lp) \
  __builtin_amdgcn_global_load_lds((const __attribute__((address_space(1))) unsigned int*)(gp), \
                                   (__attribute__((address_space(3))) unsigned int*)(lp), 16, 0, 0)

__device__ __forceinline__ ushort_t f2bf(float f) {
  union { float f; unsigned u; } v; v.f = f;
  unsigned r = v.u + 0x7fffu + ((v.u >> 16) & 1u);
  return (ushort_t)(r >> 16);
}
__device__ __forceinline__ float b2f(ushort_t u) {
  union { unsigned u; float f; } v; v.u = ((unsigned)u) << 16; return v.f;
}
__device__ __forceinline__ float fast_tanh(float x) {
  float e = __expf(2.0f * x);
  return 1.0f - 2.0f * __builtin_amdgcn_rcpf(e + 1.0f);
}
__device__ __forceinline__ uint2 pack_fp8x8(const float* v) {
  int a = __builtin_amdgcn_cvt_pk_fp8_f32(v[0], v[1], 0, false);
  a = __builtin_amdgcn_cvt_pk_fp8_f32(v[2], v[3], a, true);
  int b = __builtin_amdgcn_cvt_pk_fp8_f32(v[4], v[5], 0, false);
  b = __builtin_amdgcn_cvt_pk_fp8_f32(v[6], v[7], b, true);
  return make_uint2((unsigned)a, (unsigned)b);
}
__device__ __forceinline__ void fp8x4_to_f32(unsigned q, float* o) {
  o[0] = __builtin_amdgcn_cvt_f32_fp8(q, 0);
  o[1] = __builtin_amdgcn_cvt_f32_fp8(q, 1);
  o[2] = __builtin_amdgcn_cvt_f32_fp8(q, 2);
  o[3] = __builtin_amdgcn_cvt_f32_fp8(q, 3);
}
__device__ __forceinline__ void fp8x8_to_f32(uint2 q, float* o) {
  fp8x4_to_f32(q.x, o); fp8x4_to_f32(q.y, o + 4);
}

// ---------------- weight transpose (K x N fp32 -> N x K bf16) ----------------
__global__ void transpose_bf16(const float* __restrict__ in, ushort_t* __restrict__ out) {
  __shared__ float tile[32][33];
  const int bx = blockIdx.x * 32, by = blockIdx.y * 32;
  const int tx = threadIdx.x, ty = threadIdx.y;
#pragma unroll
  for (int i = 0; i < 32; i += 8)
    tile[ty + i][tx] = in[(size_t)(by + ty + i) * 1024 + bx + tx];
  __syncthreads();
#pragma unroll
  for (int i = 0; i < 32; i += 8)
    out[(size_t)(bx + ty + i) * 1024 + by + tx] = f2bf(tile[tx][ty + i]);
}

// ------------- weight transpose -> fp8 x32 (K x N fp32 -> N x K e4m3) -------
__global__ void transpose_fp8(const float* __restrict__ in, u8* __restrict__ out) {
  __shared__ float tile[32][33];
  const int bx = blockIdx.x * 32, by = blockIdx.y * 32;
  const int tx = threadIdx.x, ty = threadIdx.y;
#pragma unroll
  for (int i = 0; i < 32; i += 8)
    tile[ty + i][tx] = in[(size_t)(by + ty + i) * 1024 + bx + tx];
  __syncthreads();
#pragma unroll
  for (int i = 0; i < 32; i += 8) {
    const float v = 32.f * tile[tx][ty + i];
    int r = __builtin_amdgcn_cvt_pk_fp8_f32(v, v, 0, false);
    out[(size_t)(bx + ty + i) * 1024 + by + tx] = (u8)(r & 0xFF);
  }
}

// ---------------- fp32 -> bf16 convert ----------------
__global__ void conv_bf16(const float* __restrict__ in, ushort_t* __restrict__ out) {
  size_t i = ((size_t)blockIdx.x * 256 + threadIdx.x) * 4;
  float4 v = *(const float4*)&in[i];
  ushort4 o;
  o.x = f2bf(v.x); o.y = f2bf(v.y); o.z = f2bf(v.z); o.w = f2bf(v.w);
  *(ushort4*)&out[i] = o;
}

// ---------------- c31 = b3 @ W1a ----------------
__global__ void c31_kernel(const ushort_t* __restrict__ W1t, const float* __restrict__ b3,
                           float* __restrict__ c31) {
  const int j = blockIdx.x * 256 + threadIdx.x;
  float acc = 0.f;
  for (int c = 0; c < 128; ++c) {
    const us8 w = *(const us8*)&W1t[(size_t)j * 1024 + c * 8];
    const f32x8 b = *(const f32x8*)&b3[c * 8];
#pragma unroll
    for (int e = 0; e < 8; ++e) acc += b2f(w[e]) * b[e];
  }
  c31[j] = acc;
}

// ---------------- step-9 XT fold: XT += x2a + 2*x2b + 2*x2c + x2d ----------------
__global__ void xtfold(const u8* __restrict__ a, const u8* __restrict__ b,
                       const u8* __restrict__ c, const u8* __restrict__ d,
                       ushort_t* __restrict__ XT) {
  const size_t i = ((size_t)blockIdx.x * 256 + threadIdx.x) * 8;
  float va[8], vb[8], vc[8], vd[8];
  fp8x8_to_f32(*(const uint2*)&a[i], va);
  fp8x8_to_f32(*(const uint2*)&b[i], vb);
  fp8x8_to_f32(*(const uint2*)&c[i], vc);
  fp8x8_to_f32(*(const uint2*)&d[i], vd);
  const us8 xo = *(const us8*)&XT[i];
  us8 xn;
#pragma unroll
  for (int e = 0; e < 8; ++e)
    xn[e] = f2bf(b2f(xo[e]) + va[e] + 2.f * (vb[e] + vc[e]) + vd[e]);
  *(us8*)&XT[i] = xn;
}

// =================== bf16 GEMM (modes 0,1,5) — proven core ===================
// MODE 0: out8 = fp8(32*C)            (Bt31 precompute)
// MODE 1: outb = bf16(C) [hW1]; out8 = fp8(tanh(C + bias)) [x1 @ t=0]
// MODE 5: outf = h0f + DT/6*C + bias  (final fp32 h)
template<int MODE>
__global__ void __launch_bounds__(256, 2)
gemm_bf16(const ushort_t* __restrict__ Ag, const ushort_t* __restrict__ Bg,
          const float* __restrict__ bias,
          ushort_t* __restrict__ outb, u8* __restrict__ out8,
          const float* __restrict__ h0f, float* __restrict__ outf)
{
  constexpr int K = 1024, NCOL = 1024, NT = 16;
  constexpr float DT = 0.1f;
  __shared__ __align__(16) ushort_t lds[2][16384];

  const int bid = blockIdx.x;
  const int nb = (int)gridDim.x >> 3;
  const int logical = (bid & 7) * nb + (bid >> 3);
  const int bm0 = (logical >> 3) * 128;
  const int bn0 = (logical & 7) * 128;

  const int tid = threadIdx.x;
  const int w = tid >> 6, l = tid & 63;
  const int wr = w >> 1, wc = w & 1;

  const int srow = l >> 3;
  const int sclog = (l & 7) ^ srow;
  const size_t gA0 = (size_t)(bm0 + w * 32 + srow) * K + sclog * 8;
  const size_t gB0 = (size_t)(bn0 + w * 32 + srow) * K + sclog * 8;
  const int ldsAo = w * 2048 + l * 8;
  const int ldsBo = 8192 + w * 2048 + l * 8;

#define STAGEB(s, t1) do { \
    const ushort_t* ga = Ag + gA0 + (size_t)(t1) * 64; \
    const ushort_t* gb = Bg + gB0 + (size_t)(t1) * 64; \
    GLOAD16(ga,          &lds[s][ldsAo]); \
    GLOAD16(ga + 8 * K,  &lds[s][ldsAo + 512]); \
    GLOAD16(ga + 16 * K, &lds[s][ldsAo + 1024]); \
    GLOAD16(ga + 24 * K, &lds[s][ldsAo + 1536]); \
    GLOAD16(gb,          &lds[s][ldsBo]); \
    GLOAD16(gb + 8 * K,  &lds[s][ldsBo + 512]); \
    GLOAD16(gb + 16 * K, &lds[s][ldsBo + 1024]); \
    GLOAD16(gb + 24 * K, &lds[s][ldsBo + 1536]); } while (0)

  const int r = l & 15, kb = l >> 4, xr = r & 7;
  const int aRow = (wr * 64 + r) * 64;
  const int bRow = 8192 + (wc * 64 + r) * 64;
  const int c0 = ((0 | kb) ^ xr) * 8;
  const int c1 = ((4 | kb) ^ xr) * 8;

  f32x4 acc[4][4];
#pragma unroll
  for (int m = 0; m < 4; ++m)
#pragma unroll
    for (int n = 0; n < 4; ++n) acc[m][n] = (f32x4){0.f, 0.f, 0.f, 0.f};

  STAGEB(0, 0);

  for (int t = 0; t < NT; ++t) {
    const int cur = t & 1;
    __builtin_amdgcn_s_barrier();
    if (t + 1 < NT) {
      STAGEB(cur ^ 1, t + 1);
      asm volatile("s_waitcnt vmcnt(8)" ::: "memory");
    } else {
      asm volatile("s_waitcnt vmcnt(0)" ::: "memory");
    }
    __builtin_amdgcn_s_barrier();
    __builtin_amdgcn_sched_barrier(0);

    const ushort_t* Lb = &lds[cur][0];
    bf16x8 av[4], bv[4];
#pragma unroll
    for (int m = 0; m < 4; ++m) av[m] = *(const bf16x8*)(Lb + aRow + m * 1024 + c0);
#pragma unroll
    for (int n = 0; n < 4; ++n) bv[n] = *(const bf16x8*)(Lb + bRow + n * 1024 + c0);
    __builtin_amdgcn_s_setprio(1);
#pragma unroll
    for (int m = 0; m < 4; ++m)
#pragma unroll
      for (int n = 0; n < 4; ++n)
        acc[m][n] = __builtin_amdgcn_mfma_f32_16x16x32_bf16(av[m], bv[n], acc[m][n], 0, 0, 0);
    __builtin_amdgcn_s_setprio(0);
#pragma unroll
    for (int m = 0; m < 4; ++m) av[m] = *(const bf16x8*)(Lb + aRow + m * 1024 + c1);
#pragma unroll
    for (int n = 0; n < 4; ++n) bv[n] = *(const bf16x8*)(Lb + bRow + n * 1024 + c1);
    __builtin_amdgcn_s_setprio(1);
#pragma unroll
    for (int m = 0; m < 4; ++m)
#pragma unroll
      for (int n = 0; n < 4; ++n)
        acc[m][n] = __builtin_amdgcn_mfma_f32_16x16x32_bf16(av[m], bv[n], acc[m][n], 0, 0, 0);
    __builtin_amdgcn_s_setprio(0);
  }
#undef STAGEB

  __syncthreads();
  ushort_t* C = &lds[0][0];
  const int er = (l >> 4) * 4;
  const int ec = l & 15;
#pragma unroll
  for (int n = 0; n < 4; ++n) {
    const int lc = wc * 64 + n * 16 + ec;
#pragma unroll
    for (int m = 0; m < 4; ++m) {
#pragma unroll
      for (int j = 0; j < 4; ++j) {
        const int lr = wr * 64 + m * 16 + er + j;
        C[lr * 136 + lc] = f2bf(acc[m][n][j]);
      }
    }
  }
  __syncthreads();

  constexpr float DT6 = DT / 6.f;
#pragma unroll
  for (int i = 0; i < 8; ++i) {
    const int chunk = tid + i * 256;
    const int row = chunk >> 4;
    const int cc = chunk & 15;
    const int col0 = bn0 + cc * 8;
    const us8 kv8 = *(const us8*)&C[row * 136 + cc * 8];
    const size_t gidx = (size_t)(bm0 + row) * NCOL + col0;

    if (MODE == 0) {
      float v[8];
#pragma unroll
      for (int e = 0; e < 8; ++e) v[e] = 32.f * b2f(kv8[e]);
      *(uint2*)&out8[gidx] = pack_fp8x8(v);
    } else if (MODE == 1) {
      const f32x8 b = *(const f32x8*)&bias[col0];
      float v[8];
#pragma unroll
      for (int e = 0; e < 8; ++e) v[e] = fast_tanh(b2f(kv8[e]) + b[e]);
      *(us8*)&outb[gidx] = kv8;                 // hW1 (bf16)
      *(uint2*)&out8[gidx] = pack_fp8x8(v);     // x1 (fp8)
    } else {  // MODE 5
      const f32x8 b = *(const f32x8*)&bias[col0];
      const f32x8 h8 = *(const f32x8*)&h0f[gidx];
      f32x8 o;
#pragma unroll
      for (int e = 0; e < 8; ++e) o[e] = h8[e] + DT6 * b2f(kv8[e]) + b[e];
      *(f32x8*)&outf[gidx] = o;
    }
  }
}

// =================== MX-fp8 GEMM (modes 2,3,4) ===================
// C[i][j] = sum_k A[i][k]*Bt[j][k]*2^-5 via mfma_scale (B stored x32).
// MODE 2: out8 = fp8(tanh(C + bias))                      (x2 stage buffer)
// MODE 3: g = C; GS(bfio) = flag ? g : GS + p0*g;
//         out8 = fp8(tanh(hW1 + p1*(g + c31) + b + p2*wl))
// MODE 4: g4 = C; hn = hW1 + DT/6*(GS + g4) + DT*c31; hW1w = bf16(hn);
//         out8 = fp8(tanh(hn + b + p2*wl));
//         XT(bfio) = (flag ? 0 : XT) + x2a + 2*x2b + 2*x2c + Ag  (fp8 reads)
template<int MODE>
__global__ void __launch_bounds__(256, 2)
gemm_fp8(const u8* __restrict__ Ag, const u8* __restrict__ Bg,
         const float* __restrict__ bias, const float* __restrict__ wl,
         const float* __restrict__ c31,
         const ushort_t* __restrict__ hW1r, const ushort_t* __restrict__ GSr,
         const u8* __restrict__ x2a, const u8* __restrict__ x2b, const u8* __restrict__ x2c,
         u8* __restrict__ out8, ushort_t* __restrict__ bfio, ushort_t* __restrict__ hW1w,
         float p0, float p1, float p2, int flag)
{
  constexpr int NT = 16;  // BK = 64 fp8 bytes
  constexpr float DT = 0.1f, DT6 = DT / 6.f;
  __shared__ __align__(16) u8 bufs[2][16384];
  __shared__ __align__(16) ushort_t Cst[128 * 136];

  const int bid = blockIdx.x;
  const int nb = (int)gridDim.x >> 3;
  const int logical = (bid & 7) * nb + (bid >> 3);
  const int bm0 = (logical >> 3) * 128;
  const int bn0 = (logical & 7) * 128;

  const int tid = threadIdx.x;
  const int w = tid >> 6, l = tid & 63;
  const int wr = w >> 1, wc = w & 1;
  const int l31 = l & 31, kg = l >> 5;

  auto srcoff = [](int slot) -> int {
    int rp = slot >> 3, p = slot & 7, q = p ^ (rp & 7);
    return (2 * rp + (q >> 2)) * 1024 + (q & 3) * 16;
  };
  const int so0 = srcoff(tid), so1 = srcoff(256 + tid);
  const u8* gA = Ag + (size_t)bm0 * 1024;
  const u8* gB = Bg + (size_t)bn0 * 1024;
  const int ld0 = tid * 16, ld1 = 4096 + tid * 16;

#define STAGEF(s, t1) do { \
    GLOAD16(gA + so0 + (t1) * 64, &bufs[s][ld0]); \
    GLOAD16(gA + so1 + (t1) * 64, &bufs[s][ld1]); \
    GLOAD16(gB + so0 + (t1) * 64, &bufs[s][8192 + ld0]); \
    GLOAD16(gB + so1 + (t1) * 64, &bufs[s][8192 + ld1]); } while (0)

  auto ldsAddr = [](int r2, int kc) -> int {
    int q = ((r2 & 1) << 2) | kc; int p = q ^ ((r2 >> 1) & 7);
    return (r2 >> 1) * 128 + p * 16;
  };
  const int kc2 = kg * 2;
  const int ra0 = wr * 64 + l31, ra1 = ra0 + 32;
  const int rb0 = wc * 64 + l31, rb1 = rb0 + 32;
  const int aA00 = ldsAddr(ra0, kc2), aA01 = ldsAddr(ra0, kc2 + 1);
  const int aA10 = ldsAddr(ra1, kc2), aA11 = ldsAddr(ra1, kc2 + 1);
  const int bA00 = 8192 + ldsAddr(rb0, kc2), bA01 = 8192 + ldsAddr(rb0, kc2 + 1);
  const int bA10 = 8192 + ldsAddr(rb1, kc2), bA11 = 8192 + ldsAddr(rb1, kc2 + 1);

  f32x16 acc00, acc01, acc10, acc11;
#pragma unroll
  for (int i = 0; i < 16; ++i) { acc00[i] = 0.f; acc01[i] = 0.f; acc10[i] = 0.f; acc11[i] = 0.f; }

#define LD8(dst, o0, o1) do { \
    i32x4 lo_ = *(const i32x4*)(Lb + (o0)); \
    i32x4 hi_ = *(const i32x4*)(Lb + (o1)); \
    dst = (i32x8){lo_[0], lo_[1], lo_[2], lo_[3], hi_[0], hi_[1], hi_[2], hi_[3]}; } while (0)

  STAGEF(0, 0);

  for (int t = 0; t < NT; ++t) {
    const int cur = t & 1;
    __builtin_amdgcn_s_barrier();
    if (t + 1 < NT) {
      STAGEF(cur ^ 1, t + 1);
      asm volatile("s_waitcnt vmcnt(4)" ::: "memory");
    } else {
      asm volatile("s_waitcnt vmcnt(0)" ::: "memory");
    }
    __builtin_amdgcn_s_barrier();
    __builtin_amdgcn_sched_barrier(0);

    const u8* Lb = &bufs[cur][0];
    i32x8 a0, a1, b0, b1;
    LD8(a0, aA00, aA01);
    LD8(a1, aA10, aA11);
    LD8(b0, bA00, bA01);
    LD8(b1, bA10, bA11);
    __builtin_amdgcn_s_setprio(1);
    acc00 = __builtin_amdgcn_mfma_scale_f32_32x32x64_f8f6f4(a0, b0, acc00, 0, 0, 0, SCALE_ONE, 0, SCALE_INV32);
    acc01 = __builtin_amdgcn_mfma_scale_f32_32x32x64_f8f6f4(a0, b1, acc01, 0, 0, 0, SCALE_ONE, 0, SCALE_INV32);
    acc10 = __builtin_amdgcn_mfma_scale_f32_32x32x64_f8f6f4(a1, b0, acc10, 0, 0, 0, SCALE_ONE, 0, SCALE_INV32);
    acc11 = __builtin_amdgcn_mfma_scale_f32_32x32x64_f8f6f4(a1, b1, acc11, 0, 0, 0, SCALE_ONE, 0, SCALE_INV32);
    __builtin_amdgcn_s_setprio(0);
  }
#undef STAGEF

  // ---- hoisted epilogue state reads: overlap Cst staging + early epilogue ----
  us8 hw_pre[8], gs_pre[8];
  if (MODE == 3 || MODE == 4) {
#pragma unroll
    for (int i = 0; i < 8; ++i) {
      const int chunk = tid + i * 256;
      const size_t gidx = (size_t)(bm0 + (chunk >> 4)) * 1024 + bn0 + (chunk & 15) * 8;
      hw_pre[i] = *(const us8*)&hW1r[gidx];
    }
  }
  if (MODE == 3 && !flag) {
#pragma unroll
    for (int i = 0; i < 8; ++i) {
      const int chunk = tid + i * 256;
      const size_t gidx = (size_t)(bm0 + (chunk >> 4)) * 1024 + bn0 + (chunk & 15) * 8;
      gs_pre[i] = *(const us8*)&bfio[gidx];
    }
  }
  if (MODE == 4) {
#pragma unroll
    for (int i = 0; i < 8; ++i) {
      const int chunk = tid + i * 256;
      const size_t gidx = (size_t)(bm0 + (chunk >> 4)) * 1024 + bn0 + (chunk & 15) * 8;
      gs_pre[i] = *(const us8*)&GSr[gidx];
    }
  }

  // ---- stage raw bf16(C) to LDS; 32x32 C/D layout ----
#define STORE_ACC(A_, mm, nn) do { \
    _Pragma("unroll") \
    for (int reg = 0; reg < 16; ++reg) { \
      const int lrow = wr * 64 + (mm) * 32 + (reg & 3) + 8 * (reg >> 2) + 4 * kg; \
      const int lcol = wc * 64 + (nn) * 32 + l31; \
      Cst[lrow * 136 + lcol] = f2bf(A_[reg]); } } while (0)
  STORE_ACC(acc00, 0, 0);
  STORE_ACC(acc01, 0, 1);
  STORE_ACC(acc10, 1, 0);
  STORE_ACC(acc11, 1, 1);
#undef STORE_ACC
  __syncthreads();

#pragma unroll
  for (int i = 0; i < 8; ++i) {
    const int chunk = tid + i * 256;
    const int row = chunk >> 4;
    const int cc = chunk & 15;
    const int col0 = bn0 + cc * 8;
    const us8 kv8 = *(const us8*)&Cst[row * 136 + cc * 8];
    const size_t gidx = (size_t)(bm0 + row) * 1024 + col0;

    if (MODE == 2) {
      const f32x8 b = *(const f32x8*)&bias[col0];
      float x2v[8];
#pragma unroll
      for (int e = 0; e < 8; ++e) x2v[e] = fast_tanh(b2f(kv8[e]) + b[e]);
      *(uint2*)&out8[gidx] = pack_fp8x8(x2v);
    } else if (MODE == 3) {
      const f32x8 b  = *(const f32x8*)&bias[col0];
      const f32x8 wv = *(const f32x8*)&wl[col0];
      const f32x8 cv = *(const f32x8*)&c31[col0];
      const us8 hw = hw_pre[i];
      float x1v[8]; us8 gs;
      if (flag) {
#pragma unroll
        for (int e = 0; e < 8; ++e) {
          const float g = b2f(kv8[e]);
          gs[e] = f2bf(g);
          x1v[e] = fast_tanh(b2f(hw[e]) + p1 * (g + cv[e]) + b[e] + p2 * wv[e]);
        }
      } else {
        const us8 og = gs_pre[i];
#pragma unroll
        for (int e = 0; e < 8; ++e) {
          const float g = b2f(kv8[e]);
          gs[e] = f2bf(b2f(og[e]) + p0 * g);
          x1v[e] = fast_tanh(b2f(hw[e]) + p1 * (g + cv[e]) + b[e] + p2 * wv[e]);
        }
      }
      *(us8*)&bfio[gidx] = gs;
      *(uint2*)&out8[gidx] = pack_fp8x8(x1v);
    } else {  // MODE 4
      const f32x8 b  = *(const f32x8*)&bias[col0];
      const f32x8 wv = *(const f32x8*)&wl[col0];
      const f32x8 cv = *(const f32x8*)&c31[col0];
      const us8 hw = hw_pre[i];
      const us8 gs = gs_pre[i];
      // XT fold: x2a + 2*x2b + 2*x2c + x2d(=Ag)
      float va[8], vb[8], vc[8], vd[8];
      fp8x8_to_f32(*(const uint2*)&x2a[gidx], va);
      fp8x8_to_f32(*(const uint2*)&x2b[gidx], vb);
      fp8x8_to_f32(*(const uint2*)&x2c[gidx], vc);
      fp8x8_to_f32(*(const uint2*)&Ag[gidx], vd);
      us8 xtn;
      if (flag) {
#pragma unroll
        for (int e = 0; e < 8; ++e)
          xtn[e] = f2bf(va[e] + 2.f * (vb[e] + vc[e]) + vd[e]);
      } else {
        const us8 xo = *(const us8*)&bfio[gidx];
#pragma unroll
        for (int e = 0; e < 8; ++e)
          xtn[e] = f2bf(b2f(xo[e]) + va[e] + 2.f * (vb[e] + vc[e]) + vd[e]);
      }
      *(us8*)&bfio[gidx] = xtn;
      // h-state update
      float x1v[8]; us8 o1;
#pragma unroll
      for (int e = 0; e < 8; ++e) {
        const float hn = b2f(hw[e]) + DT6 * (b2f(gs[e]) + b2f(kv8[e])) + DT * cv[e];
        o1[e] = f2bf(hn);
        x1v[e] = fast_tanh(hn + b[e] + p2 * wv[e]);
      }
      *(us8*)&hW1w[gidx] = o1;
      *(uint2*)&out8[gidx] = pack_fp8x8(x1v);
    }
  }
}

extern "C" void kernel_launch(void* const* d_in, const int* in_sizes, int n_in,
                              void* d_out, int out_size, void* d_ws, size_t ws_size,
                              hipStream_t stream) {
  (void)in_sizes; (void)n_in; (void)out_size; (void)ws_size;
  const float* h_in = (const float*)d_in[0];
  const float* W1   = (const float*)d_in[1];   // 1025 x 1024
  const float* b1   = (const float*)d_in[2];
  const float* W2   = (const float*)d_in[3];
  const float* b2   = (const float*)d_in[4];
  const float* W3   = (const float*)d_in[5];
  const float* b3   = (const float*)d_in[6];
  const float* W1last = W1 + (size_t)1024 * 1024;

  char* ws = (char*)d_ws;
  ushort_t* W1t   = (ushort_t*)(ws);                   // 2 MiB (reused for W3^T at end)
  u8*       W2t8  = (u8*)      (ws + (2ull << 20));    // 1 MiB fp8 x32
  u8*       Bt318 = (u8*)      (ws + (3ull << 20));    // 1 MiB fp8 x32
  float*    c31   = (float*)   (ws + (4ull << 20));    // 4 KiB
  ushort_t* hW1b  = (ushort_t*)(ws + (8ull << 20));    // 16 MiB bf16
  u8*       x1    = (u8*)      (ws + (24ull << 20));   // 8 MiB fp8
  u8*       x2s0  = (u8*)      (ws + (32ull << 20));   // 8 MiB fp8
  u8*       x2s1  = (u8*)      (ws + (40ull << 20));   // 8 MiB fp8
  u8*       x2s2  = (u8*)      (ws + (48ull << 20));   // 8 MiB fp8
  u8*       x2s3  = (u8*)      (ws + (56ull << 20));   // 8 MiB fp8
  ushort_t* XT    = (ushort_t*)(ws + (64ull << 20));   // 16 MiB bf16 (W3b transient)
  ushort_t* GS    = (ushort_t*)d_out;                  // bf16, d_out low half
  ushort_t* hb    = (ushort_t*)d_out;                  // bf16 h (dead after MODE1)
  float*    OUT   = (float*)d_out;

  const float dt = 0.1f;
  constexpr int GRID = 512, BLK = 256;
  dim3 tb(32, 8), tg(32, 32);

  // ---- precompute ----
  transpose_bf16<<<tg, tb, 0, stream>>>(W1, W1t);
  transpose_fp8 <<<tg, tb, 0, stream>>>(W2, W2t8);
  conv_bf16<<<1024, 256, 0, stream>>>(W3, XT);         // W3b transient in XT slot
  conv_bf16<<<8192, 256, 0, stream>>>(h_in, hb);
  c31_kernel<<<4, 256, 0, stream>>>(W1t, b3, c31);
  gemm_bf16<0><<<64, BLK, 0, stream>>>(W1t, XT, nullptr, nullptr, Bt318, nullptr, nullptr);
  gemm_bf16<1><<<GRID, BLK, 0, stream>>>(hb, W1t, b1, hW1b, x1, nullptr, nullptr);

  for (int step = 0; step < 10; ++step) {
    const float t0 = step * dt;
    // stage 1
    gemm_fp8<2><<<GRID, BLK, 0, stream>>>(x1, W2t8, b2, nullptr, nullptr, nullptr, nullptr,
                                          nullptr, nullptr, nullptr, x2s0, nullptr, nullptr,
                                          0.f, 0.f, 0.f, 0);
    gemm_fp8<3><<<GRID, BLK, 0, stream>>>(x2s0, Bt318, b1, W1last, c31, hW1b, nullptr,
                                          nullptr, nullptr, nullptr, x1, GS, nullptr,
                                          1.f, 0.5f * dt, t0 + 0.5f * dt, 1);
    // stage 2
    gemm_fp8<2><<<GRID, BLK, 0, stream>>>(x1, W2t8, b2, nullptr, nullptr, nullptr, nullptr,
                                          nullptr, nullptr, nullptr, x2s1, nullptr, nullptr,
                                          0.f, 0.f, 0.f, 0);
    gemm_fp8<3><<<GRID, BLK, 0, stream>>>(x2s1, Bt318, b1, W1last, c31, hW1b, nullptr,
                                          nullptr, nullptr, nullptr, x1, GS, nullptr,
                                          2.f, 0.5f * dt, t0 + 0.5f * dt, 0);
    // stage 3
    gemm_fp8<2><<<GRID, BLK, 0, stream>>>(x1, W2t8, b2, nullptr, nullptr, nullptr, nullptr,
                                          nullptr, nullptr, nullptr, x2s2, nullptr, nullptr,
                                          0.f, 0.f, 0.f, 0);
    gemm_fp8<3><<<GRID, BLK, 0, stream>>>(x2s2, Bt318, b1, W1last, c31, hW1b, nullptr,
                                          nullptr, nullptr, nullptr, x1, GS, nullptr,
                                          2.f, dt, t0 + dt, 0);
    // stage 4
    gemm_fp8<2><<<GRID, BLK, 0, stream>>>(x1, W2t8, b2, nullptr, nullptr, nullptr, nullptr,
                                          nullptr, nullptr, nullptr, x2s3, nullptr, nullptr,
                                          0.f, 0.f, 0.f, 0);
    if (step < 9) {
      gemm_fp8<4><<<GRID, BLK, 0, stream>>>(x2s3, Bt318, b1, W1last, c31, hW1b, GS,
                                            x2s0, x2s1, x2s2, x1, XT, hW1b,
                                            0.f, 0.f, t0 + dt, (step == 0));
    }
  }
  // step-9 XT contribution (no MODE4 needed — hW1 no longer used)
  xtfold<<<4096, 256, 0, stream>>>(x2s0, x2s1, x2s2, x2s3, XT);

  // final: h = h0 + dt/6 * XT@W3 + b3
  transpose_bf16<<<tg, tb, 0, stream>>>(W3, W1t);
  gemm_bf16<5><<<GRID, BLK, 0, stream>>>(XT, W1t, b3, nullptr, nullptr, h_in, OUT);
}

// Round 9
// 1492.142 us; speedup vs baseline: 2.3106x; 1.0629x over previous
//
#include <hip/hip_runtime.h>

// NeuralODE RK4, restructured algebra (W31 merged GEMM, hW1 state, XT deferred
// reconstruction) + MX-fp8 GEMM core. R9: fp8 GEMM K-tile BK 64->128 bytes
// (NT 16->8): halves barrier pairs (the measured ~2300cyc/tile stall), LDS
// 2x(16KB A+16KB B)=64KB with C-staging overlaid on the dead staging buffers
// so occupancy stays 2 blocks/CU.

typedef __attribute__((ext_vector_type(8))) __bf16 bf16x8;
typedef __attribute__((ext_vector_type(4))) float f32x4;
typedef __attribute__((ext_vector_type(8))) float f32x8;
typedef __attribute__((ext_vector_type(16))) float f32x16;
typedef __attribute__((ext_vector_type(8))) unsigned short us8;
typedef __attribute__((ext_vector_type(4))) int i32x4;
typedef __attribute__((ext_vector_type(8))) int i32x8;
typedef unsigned short ushort_t;
typedef unsigned char u8;

#define SCALE_ONE  0x7F7F7F7Fu   // E8M0 1.0 per byte
#define SCALE_INV32 0x7A7A7A7Au  // E8M0 2^-5 per byte

#define GLOAD16(gp, lp) \
  __builtin_amdgcn_global_load_lds((const __attribute__((address_space(1))) unsigned int*)(gp), \
                                   (__attribute__((address_space(3))) unsigned int*)(lp), 16, 0, 0)

__device__ __forceinline__ ushort_t f2bf(float f) {
  union { float f; unsigned u; } v; v.f = f;
  unsigned r = v.u + 0x7fffu + ((v.u >> 16) & 1u);
  return (ushort_t)(r >> 16);
}
__device__ __forceinline__ float b2f(ushort_t u) {
  union { unsigned u; float f; } v; v.u = ((unsigned)u) << 16; return v.f;
}
__device__ __forceinline__ float fast_tanh(float x) {
  float e = __expf(2.0f * x);
  return 1.0f - 2.0f * __builtin_amdgcn_rcpf(e + 1.0f);
}
__device__ __forceinline__ uint2 pack_fp8x8(const float* v) {
  int a = __builtin_amdgcn_cvt_pk_fp8_f32(v[0], v[1], 0, false);
  a = __builtin_amdgcn_cvt_pk_fp8_f32(v[2], v[3], a, true);
  int b = __builtin_amdgcn_cvt_pk_fp8_f32(v[4], v[5], 0, false);
  b = __builtin_amdgcn_cvt_pk_fp8_f32(v[6], v[7], b, true);
  return make_uint2((unsigned)a, (unsigned)b);
}
__device__ __forceinline__ void fp8x4_to_f32(unsigned q, float* o) {
  o[0] = __builtin_amdgcn_cvt_f32_fp8(q, 0);
  o[1] = __builtin_amdgcn_cvt_f32_fp8(q, 1);
  o[2] = __builtin_amdgcn_cvt_f32_fp8(q, 2);
  o[3] = __builtin_amdgcn_cvt_f32_fp8(q, 3);
}
__device__ __forceinline__ void fp8x8_to_f32(uint2 q, float* o) {
  fp8x4_to_f32(q.x, o); fp8x4_to_f32(q.y, o + 4);
}

// ---------------- weight transpose (K x N fp32 -> N x K bf16) ----------------
__global__ void transpose_bf16(const float* __restrict__ in, ushort_t* __restrict__ out) {
  __shared__ float tile[32][33];
  const int bx = blockIdx.x * 32, by = blockIdx.y * 32;
  const int tx = threadIdx.x, ty = threadIdx.y;
#pragma unroll
  for (int i = 0; i < 32; i += 8)
    tile[ty + i][tx] = in[(size_t)(by + ty + i) * 1024 + bx + tx];
  __syncthreads();
#pragma unroll
  for (int i = 0; i < 32; i += 8)
    out[(size_t)(bx + ty + i) * 1024 + by + tx] = f2bf(tile[tx][ty + i]);
}

// ------------- weight transpose -> fp8 x32 (K x N fp32 -> N x K e4m3) -------
__global__ void transpose_fp8(const float* __restrict__ in, u8* __restrict__ out) {
  __shared__ float tile[32][33];
  const int bx = blockIdx.x * 32, by = blockIdx.y * 32;
  const int tx = threadIdx.x, ty = threadIdx.y;
#pragma unroll
  for (int i = 0; i < 32; i += 8)
    tile[ty + i][tx] = in[(size_t)(by + ty + i) * 1024 + bx + tx];
  __syncthreads();
#pragma unroll
  for (int i = 0; i < 32; i += 8) {
    const float v = 32.f * tile[tx][ty + i];
    int r = __builtin_amdgcn_cvt_pk_fp8_f32(v, v, 0, false);
    out[(size_t)(bx + ty + i) * 1024 + by + tx] = (u8)(r & 0xFF);
  }
}

// ---------------- fp32 -> bf16 convert ----------------
__global__ void conv_bf16(const float* __restrict__ in, ushort_t* __restrict__ out) {
  size_t i = ((size_t)blockIdx.x * 256 + threadIdx.x) * 4;
  float4 v = *(const float4*)&in[i];
  ushort4 o;
  o.x = f2bf(v.x); o.y = f2bf(v.y); o.z = f2bf(v.z); o.w = f2bf(v.w);
  *(ushort4*)&out[i] = o;
}

// ---------------- c31 = b3 @ W1a ----------------
__global__ void c31_kernel(const ushort_t* __restrict__ W1t, const float* __restrict__ b3,
                           float* __restrict__ c31) {
  const int j = blockIdx.x * 256 + threadIdx.x;
  float acc = 0.f;
  for (int c = 0; c < 128; ++c) {
    const us8 w = *(const us8*)&W1t[(size_t)j * 1024 + c * 8];
    const f32x8 b = *(const f32x8*)&b3[c * 8];
#pragma unroll
    for (int e = 0; e < 8; ++e) acc += b2f(w[e]) * b[e];
  }
  c31[j] = acc;
}

// ---------------- step-9 XT fold: XT += x2a + 2*x2b + 2*x2c + x2d ----------------
__global__ void xtfold(const u8* __restrict__ a, const u8* __restrict__ b,
                       const u8* __restrict__ c, const u8* __restrict__ d,
                       ushort_t* __restrict__ XT) {
  const size_t i = ((size_t)blockIdx.x * 256 + threadIdx.x) * 8;
  float va[8], vb[8], vc[8], vd[8];
  fp8x8_to_f32(*(const uint2*)&a[i], va);
  fp8x8_to_f32(*(const uint2*)&b[i], vb);
  fp8x8_to_f32(*(const uint2*)&c[i], vc);
  fp8x8_to_f32(*(const uint2*)&d[i], vd);
  const us8 xo = *(const us8*)&XT[i];
  us8 xn;
#pragma unroll
  for (int e = 0; e < 8; ++e)
    xn[e] = f2bf(b2f(xo[e]) + va[e] + 2.f * (vb[e] + vc[e]) + vd[e]);
  *(us8*)&XT[i] = xn;
}

// =================== bf16 GEMM (modes 0,1,5) — proven core ===================
// MODE 0: out8 = fp8(32*C)            (Bt31 precompute)
// MODE 1: outb = bf16(C) [hW1]; out8 = fp8(tanh(C + bias)) [x1 @ t=0]
// MODE 5: outf = h0f + DT/6*C + bias  (final fp32 h)
template<int MODE>
__global__ void __launch_bounds__(256, 2)
gemm_bf16(const ushort_t* __restrict__ Ag, const ushort_t* __restrict__ Bg,
          const float* __restrict__ bias,
          ushort_t* __restrict__ outb, u8* __restrict__ out8,
          const float* __restrict__ h0f, float* __restrict__ outf)
{
  constexpr int K = 1024, NCOL = 1024, NT = 16;
  constexpr float DT = 0.1f;
  __shared__ __align__(16) ushort_t lds[2][16384];

  const int bid = blockIdx.x;
  const int nb = (int)gridDim.x >> 3;
  const int logical = (bid & 7) * nb + (bid >> 3);
  const int bm0 = (logical >> 3) * 128;
  const int bn0 = (logical & 7) * 128;

  const int tid = threadIdx.x;
  const int w = tid >> 6, l = tid & 63;
  const int wr = w >> 1, wc = w & 1;

  const int srow = l >> 3;
  const int sclog = (l & 7) ^ srow;
  const size_t gA0 = (size_t)(bm0 + w * 32 + srow) * K + sclog * 8;
  const size_t gB0 = (size_t)(bn0 + w * 32 + srow) * K + sclog * 8;
  const int ldsAo = w * 2048 + l * 8;
  const int ldsBo = 8192 + w * 2048 + l * 8;

#define STAGEB(s, t1) do { \
    const ushort_t* ga = Ag + gA0 + (size_t)(t1) * 64; \
    const ushort_t* gb = Bg + gB0 + (size_t)(t1) * 64; \
    GLOAD16(ga,          &lds[s][ldsAo]); \
    GLOAD16(ga + 8 * K,  &lds[s][ldsAo + 512]); \
    GLOAD16(ga + 16 * K, &lds[s][ldsAo + 1024]); \
    GLOAD16(ga + 24 * K, &lds[s][ldsAo + 1536]); \
    GLOAD16(gb,          &lds[s][ldsBo]); \
    GLOAD16(gb + 8 * K,  &lds[s][ldsBo + 512]); \
    GLOAD16(gb + 16 * K, &lds[s][ldsBo + 1024]); \
    GLOAD16(gb + 24 * K, &lds[s][ldsBo + 1536]); } while (0)

  const int r = l & 15, kb = l >> 4, xr = r & 7;
  const int aRow = (wr * 64 + r) * 64;
  const int bRow = 8192 + (wc * 64 + r) * 64;
  const int c0 = ((0 | kb) ^ xr) * 8;
  const int c1 = ((4 | kb) ^ xr) * 8;

  f32x4 acc[4][4];
#pragma unroll
  for (int m = 0; m < 4; ++m)
#pragma unroll
    for (int n = 0; n < 4; ++n) acc[m][n] = (f32x4){0.f, 0.f, 0.f, 0.f};

  STAGEB(0, 0);

  for (int t = 0; t < NT; ++t) {
    const int cur = t & 1;
    __builtin_amdgcn_s_barrier();
    if (t + 1 < NT) {
      STAGEB(cur ^ 1, t + 1);
      asm volatile("s_waitcnt vmcnt(8)" ::: "memory");
    } else {
      asm volatile("s_waitcnt vmcnt(0)" ::: "memory");
    }
    __builtin_amdgcn_s_barrier();
    __builtin_amdgcn_sched_barrier(0);

    const ushort_t* Lb = &lds[cur][0];
    bf16x8 av[4], bv[4];
#pragma unroll
    for (int m = 0; m < 4; ++m) av[m] = *(const bf16x8*)(Lb + aRow + m * 1024 + c0);
#pragma unroll
    for (int n = 0; n < 4; ++n) bv[n] = *(const bf16x8*)(Lb + bRow + n * 1024 + c0);
    __builtin_amdgcn_s_setprio(1);
#pragma unroll
    for (int m = 0; m < 4; ++m)
#pragma unroll
      for (int n = 0; n < 4; ++n)
        acc[m][n] = __builtin_amdgcn_mfma_f32_16x16x32_bf16(av[m], bv[n], acc[m][n], 0, 0, 0);
    __builtin_amdgcn_s_setprio(0);
#pragma unroll
    for (int m = 0; m < 4; ++m) av[m] = *(const bf16x8*)(Lb + aRow + m * 1024 + c1);
#pragma unroll
    for (int n = 0; n < 4; ++n) bv[n] = *(const bf16x8*)(Lb + bRow + n * 1024 + c1);
    __builtin_amdgcn_s_setprio(1);
#pragma unroll
    for (int m = 0; m < 4; ++m)
#pragma unroll
      for (int n = 0; n < 4; ++n)
        acc[m][n] = __builtin_amdgcn_mfma_f32_16x16x32_bf16(av[m], bv[n], acc[m][n], 0, 0, 0);
    __builtin_amdgcn_s_setprio(0);
  }
#undef STAGEB

  __syncthreads();
  ushort_t* C = &lds[0][0];
  const int er = (l >> 4) * 4;
  const int ec = l & 15;
#pragma unroll
  for (int n = 0; n < 4; ++n) {
    const int lc = wc * 64 + n * 16 + ec;
#pragma unroll
    for (int m = 0; m < 4; ++m) {
#pragma unroll
      for (int j = 0; j < 4; ++j) {
        const int lr = wr * 64 + m * 16 + er + j;
        C[lr * 136 + lc] = f2bf(acc[m][n][j]);
      }
    }
  }
  __syncthreads();

  constexpr float DT6 = DT / 6.f;
#pragma unroll
  for (int i = 0; i < 8; ++i) {
    const int chunk = tid + i * 256;
    const int row = chunk >> 4;
    const int cc = chunk & 15;
    const int col0 = bn0 + cc * 8;
    const us8 kv8 = *(const us8*)&C[row * 136 + cc * 8];
    const size_t gidx = (size_t)(bm0 + row) * NCOL + col0;

    if (MODE == 0) {
      float v[8];
#pragma unroll
      for (int e = 0; e < 8; ++e) v[e] = 32.f * b2f(kv8[e]);
      *(uint2*)&out8[gidx] = pack_fp8x8(v);
    } else if (MODE == 1) {
      const f32x8 b = *(const f32x8*)&bias[col0];
      float v[8];
#pragma unroll
      for (int e = 0; e < 8; ++e) v[e] = fast_tanh(b2f(kv8[e]) + b[e]);
      *(us8*)&outb[gidx] = kv8;                 // hW1 (bf16)
      *(uint2*)&out8[gidx] = pack_fp8x8(v);     // x1 (fp8)
    } else {  // MODE 5
      const f32x8 b = *(const f32x8*)&bias[col0];
      const f32x8 h8 = *(const f32x8*)&h0f[gidx];
      f32x8 o;
#pragma unroll
      for (int e = 0; e < 8; ++e) o[e] = h8[e] + DT6 * b2f(kv8[e]) + b[e];
      *(f32x8*)&outf[gidx] = o;
    }
  }
}

// =================== MX-fp8 GEMM (modes 2,3,4), BK=128 ===================
// C[i][j] = sum_k A[i][k]*Bt[j][k]*2^-5 via mfma_scale (B stored x32).
// MODE 2: out8 = fp8(tanh(C + bias))                      (x2 stage buffer)
// MODE 3: g = C; GS(bfio) = flag ? g : GS + p0*g;
//         out8 = fp8(tanh(hW1 + p1*(g + c31) + b + p2*wl))
// MODE 4: g4 = C; hn = hW1 + DT/6*(GS + g4) + DT*c31; hW1w = bf16(hn);
//         out8 = fp8(tanh(hn + b + p2*wl));
//         XT(bfio) = (flag ? 0 : XT) + x2a + 2*x2b + 2*x2c + Ag  (fp8 reads)
template<int MODE>
__global__ void __launch_bounds__(256, 2)
gemm_fp8(const u8* __restrict__ Ag, const u8* __restrict__ Bg,
         const float* __restrict__ bias, const float* __restrict__ wl,
         const float* __restrict__ c31,
         const ushort_t* __restrict__ hW1r, const ushort_t* __restrict__ GSr,
         const u8* __restrict__ x2a, const u8* __restrict__ x2b, const u8* __restrict__ x2c,
         u8* __restrict__ out8, ushort_t* __restrict__ bfio, ushort_t* __restrict__ hW1w,
         float p0, float p1, float p2, int flag)
{
  constexpr int NT = 8;   // BK = 128 fp8 bytes
  constexpr float DT = 0.1f, DT6 = DT / 6.f;
  // per buffer: A 128x128B = 16KB | B 16KB; 2 buffers = 64KB. C-staging overlaid.
  __shared__ __align__(16) u8 bufs[2][32768];

  const int bid = blockIdx.x;
  const int nb = (int)gridDim.x >> 3;
  const int logical = (bid & 7) * nb + (bid >> 3);
  const int bm0 = (logical >> 3) * 128;
  const int bn0 = (logical & 7) * 128;

  const int tid = threadIdx.x;
  const int w = tid >> 6, l = tid & 63;
  const int wr = w >> 1, wc = w & 1;
  const int l31 = l & 31, kg = l >> 5;

  // ---- staging: slot s in [0,1024) holds (row = s>>3, phys chunk = s&7);
  //      source chunk clog = phys ^ (row&7); LDS dest linear slot*16 ----
  int so[4], ldo[4];
#pragma unroll
  for (int i = 0; i < 4; ++i) {
    const int slot = tid + i * 256;
    const int row = slot >> 3, phys = slot & 7;
    so[i] = row * 1024 + ((phys ^ (row & 7)) << 4);
    ldo[i] = slot << 4;
  }
  const u8* gA = Ag + (size_t)bm0 * 1024;
  const u8* gB = Bg + (size_t)bn0 * 1024;

#define STAGEF(s, t1) do { \
    GLOAD16(gA + so[0] + (t1) * 128, &bufs[s][ldo[0]]); \
    GLOAD16(gA + so[1] + (t1) * 128, &bufs[s][ldo[1]]); \
    GLOAD16(gA + so[2] + (t1) * 128, &bufs[s][ldo[2]]); \
    GLOAD16(gA + so[3] + (t1) * 128, &bufs[s][ldo[3]]); \
    GLOAD16(gB + so[0] + (t1) * 128, &bufs[s][16384 + ldo[0]]); \
    GLOAD16(gB + so[1] + (t1) * 128, &bufs[s][16384 + ldo[1]]); \
    GLOAD16(gB + so[2] + (t1) * 128, &bufs[s][16384 + ldo[2]]); \
    GLOAD16(gB + so[3] + (t1) * 128, &bufs[s][16384 + ldo[3]]); } while (0)

  // ---- fragment addresses: elem(row, chunk c) at row*128 + (c^(row&7))*16;
  //      lane reads 32B = chunks {kb2*4+kg*2, +1} of its row ----
  auto ldsAddr = [](int row, int c) -> int {
    return row * 128 + ((c ^ (row & 7)) << 4);
  };
  const int ra0 = wr * 64 + l31, ra1 = ra0 + 32;
  const int rb0 = wc * 64 + l31, rb1 = rb0 + 32;
  const int ck0 = kg * 2, ck1 = 4 + kg * 2;   // chunk base for kblock 0 / 1
  const int a00 = ldsAddr(ra0, ck0), a00b = ldsAddr(ra0, ck0 + 1);
  const int a10 = ldsAddr(ra1, ck0), a10b = ldsAddr(ra1, ck0 + 1);
  const int b00 = 16384 + ldsAddr(rb0, ck0), b00b = 16384 + ldsAddr(rb0, ck0 + 1);
  const int b10 = 16384 + ldsAddr(rb1, ck0), b10b = 16384 + ldsAddr(rb1, ck0 + 1);
  const int a01 = ldsAddr(ra0, ck1), a01b = ldsAddr(ra0, ck1 + 1);
  const int a11 = ldsAddr(ra1, ck1), a11b = ldsAddr(ra1, ck1 + 1);
  const int b01 = 16384 + ldsAddr(rb0, ck1), b01b = 16384 + ldsAddr(rb0, ck1 + 1);
  const int b11 = 16384 + ldsAddr(rb1, ck1), b11b = 16384 + ldsAddr(rb1, ck1 + 1);

  f32x16 acc00, acc01, acc10, acc11;
#pragma unroll
  for (int i = 0; i < 16; ++i) { acc00[i] = 0.f; acc01[i] = 0.f; acc10[i] = 0.f; acc11[i] = 0.f; }

#define LD8(dst, o0, o1) do { \
    i32x4 lo_ = *(const i32x4*)(Lb + (o0)); \
    i32x4 hi_ = *(const i32x4*)(Lb + (o1)); \
    dst = (i32x8){lo_[0], lo_[1], lo_[2], lo_[3], hi_[0], hi_[1], hi_[2], hi_[3]}; } while (0)

  STAGEF(0, 0);

  for (int t = 0; t < NT; ++t) {
    const int cur = t & 1;
    __builtin_amdgcn_s_barrier();
    if (t + 1 < NT) {
      STAGEF(cur ^ 1, t + 1);
      asm volatile("s_waitcnt vmcnt(8)" ::: "memory");
    } else {
      asm volatile("s_waitcnt vmcnt(0)" ::: "memory");
    }
    __builtin_amdgcn_s_barrier();
    __builtin_amdgcn_sched_barrier(0);

    const u8* Lb = &bufs[cur][0];
    i32x8 a0, a1, b0, b1;
    // kblock 0
    LD8(a0, a00, a00b);
    LD8(a1, a10, a10b);
    LD8(b0, b00, b00b);
    LD8(b1, b10, b10b);
    __builtin_amdgcn_s_setprio(1);
    acc00 = __builtin_amdgcn_mfma_scale_f32_32x32x64_f8f6f4(a0, b0, acc00, 0, 0, 0, SCALE_ONE, 0, SCALE_INV32);
    acc01 = __builtin_amdgcn_mfma_scale_f32_32x32x64_f8f6f4(a0, b1, acc01, 0, 0, 0, SCALE_ONE, 0, SCALE_INV32);
    acc10 = __builtin_amdgcn_mfma_scale_f32_32x32x64_f8f6f4(a1, b0, acc10, 0, 0, 0, SCALE_ONE, 0, SCALE_INV32);
    acc11 = __builtin_amdgcn_mfma_scale_f32_32x32x64_f8f6f4(a1, b1, acc11, 0, 0, 0, SCALE_ONE, 0, SCALE_INV32);
    __builtin_amdgcn_s_setprio(0);
    // kblock 1
    LD8(a0, a01, a01b);
    LD8(a1, a11, a11b);
    LD8(b0, b01, b01b);
    LD8(b1, b11, b11b);
    __builtin_amdgcn_s_setprio(1);
    acc00 = __builtin_amdgcn_mfma_scale_f32_32x32x64_f8f6f4(a0, b0, acc00, 0, 0, 0, SCALE_ONE, 0, SCALE_INV32);
    acc01 = __builtin_amdgcn_mfma_scale_f32_32x32x64_f8f6f4(a0, b1, acc01, 0, 0, 0, SCALE_ONE, 0, SCALE_INV32);
    acc10 = __builtin_amdgcn_mfma_scale_f32_32x32x64_f8f6f4(a1, b0, acc10, 0, 0, 0, SCALE_ONE, 0, SCALE_INV32);
    acc11 = __builtin_amdgcn_mfma_scale_f32_32x32x64_f8f6f4(a1, b1, acc11, 0, 0, 0, SCALE_ONE, 0, SCALE_INV32);
    __builtin_amdgcn_s_setprio(0);
  }
#undef STAGEF

  // ---- hoisted epilogue state reads: overlap Cst staging + early epilogue ----
  us8 hw_pre[8], gs_pre[8];
  if (MODE == 3 || MODE == 4) {
#pragma unroll
    for (int i = 0; i < 8; ++i) {
      const int chunk = tid + i * 256;
      const size_t gidx = (size_t)(bm0 + (chunk >> 4)) * 1024 + bn0 + (chunk & 15) * 8;
      hw_pre[i] = *(const us8*)&hW1r[gidx];
    }
  }
  if (MODE == 3 && !flag) {
#pragma unroll
    for (int i = 0; i < 8; ++i) {
      const int chunk = tid + i * 256;
      const size_t gidx = (size_t)(bm0 + (chunk >> 4)) * 1024 + bn0 + (chunk & 15) * 8;
      gs_pre[i] = *(const us8*)&bfio[gidx];
    }
  }
  if (MODE == 4) {
#pragma unroll
    for (int i = 0; i < 8; ++i) {
      const int chunk = tid + i * 256;
      const size_t gidx = (size_t)(bm0 + (chunk >> 4)) * 1024 + bn0 + (chunk & 15) * 8;
      gs_pre[i] = *(const us8*)&GSr[gidx];
    }
  }

  // ---- stage raw bf16(C) to LDS (overlaid on staging bufs — barrier first);
  //      32x32 C/D layout: col = lane&31, row = (reg&3)+8*(reg>>2)+4*(lane>>5)
  __syncthreads();
  ushort_t* Cst = (ushort_t*)&bufs[0][0];     // 128 x 136 bf16 = 34KB < 64KB
#define STORE_ACC(A_, mm, nn) do { \
    _Pragma("unroll") \
    for (int reg = 0; reg < 16; ++reg) { \
      const int lrow = wr * 64 + (mm) * 32 + (reg & 3) + 8 * (reg >> 2) + 4 * kg; \
      const int lcol = wc * 64 + (nn) * 32 + l31; \
      Cst[lrow * 136 + lcol] = f2bf(A_[reg]); } } while (0)
  STORE_ACC(acc00, 0, 0);
  STORE_ACC(acc01, 0, 1);
  STORE_ACC(acc10, 1, 0);
  STORE_ACC(acc11, 1, 1);
#undef STORE_ACC
  __syncthreads();

#pragma unroll
  for (int i = 0; i < 8; ++i) {
    const int chunk = tid + i * 256;
    const int row = chunk >> 4;
    const int cc = chunk & 15;
    const int col0 = bn0 + cc * 8;
    const us8 kv8 = *(const us8*)&Cst[row * 136 + cc * 8];
    const size_t gidx = (size_t)(bm0 + row) * 1024 + col0;

    if (MODE == 2) {
      const f32x8 b = *(const f32x8*)&bias[col0];
      float x2v[8];
#pragma unroll
      for (int e = 0; e < 8; ++e) x2v[e] = fast_tanh(b2f(kv8[e]) + b[e]);
      *(uint2*)&out8[gidx] = pack_fp8x8(x2v);
    } else if (MODE == 3) {
      const f32x8 b  = *(const f32x8*)&bias[col0];
      const f32x8 wv = *(const f32x8*)&wl[col0];
      const f32x8 cv = *(const f32x8*)&c31[col0];
      const us8 hw = hw_pre[i];
      float x1v[8]; us8 gs;
      if (flag) {
#pragma unroll
        for (int e = 0; e < 8; ++e) {
          const float g = b2f(kv8[e]);
          gs[e] = f2bf(g);
          x1v[e] = fast_tanh(b2f(hw[e]) + p1 * (g + cv[e]) + b[e] + p2 * wv[e]);
        }
      } else {
        const us8 og = gs_pre[i];
#pragma unroll
        for (int e = 0; e < 8; ++e) {
          const float g = b2f(kv8[e]);
          gs[e] = f2bf(b2f(og[e]) + p0 * g);
          x1v[e] = fast_tanh(b2f(hw[e]) + p1 * (g + cv[e]) + b[e] + p2 * wv[e]);
        }
      }
      *(us8*)&bfio[gidx] = gs;
      *(uint2*)&out8[gidx] = pack_fp8x8(x1v);
    } else {  // MODE 4
      const f32x8 b  = *(const f32x8*)&bias[col0];
      const f32x8 wv = *(const f32x8*)&wl[col0];
      const f32x8 cv = *(const f32x8*)&c31[col0];
      const us8 hw = hw_pre[i];
      const us8 gs = gs_pre[i];
      float va[8], vb[8], vc[8], vd[8];
      fp8x8_to_f32(*(const uint2*)&x2a[gidx], va);
      fp8x8_to_f32(*(const uint2*)&x2b[gidx], vb);
      fp8x8_to_f32(*(const uint2*)&x2c[gidx], vc);
      fp8x8_to_f32(*(const uint2*)&Ag[gidx], vd);
      us8 xtn;
      if (flag) {
#pragma unroll
        for (int e = 0; e < 8; ++e)
          xtn[e] = f2bf(va[e] + 2.f * (vb[e] + vc[e]) + vd[e]);
      } else {
        const us8 xo = *(const us8*)&bfio[gidx];
#pragma unroll
        for (int e = 0; e < 8; ++e)
          xtn[e] = f2bf(b2f(xo[e]) + va[e] + 2.f * (vb[e] + vc[e]) + vd[e]);
      }
      *(us8*)&bfio[gidx] = xtn;
      float x1v[8]; us8 o1;
#pragma unroll
      for (int e = 0; e < 8; ++e) {
        const float hn = b2f(hw[e]) + DT6 * (b2f(gs[e]) + b2f(kv8[e])) + DT * cv[e];
        o1[e] = f2bf(hn);
        x1v[e] = fast_tanh(hn + b[e] + p2 * wv[e]);
      }
      *(us8*)&hW1w[gidx] = o1;
      *(uint2*)&out8[gidx] = pack_fp8x8(x1v);
    }
  }
}

extern "C" void kernel_launch(void* const* d_in, const int* in_sizes, int n_in,
                              void* d_out, int out_size, void* d_ws, size_t ws_size,
                              hipStream_t stream) {
  (void)in_sizes; (void)n_in; (void)out_size; (void)ws_size;
  const float* h_in = (const float*)d_in[0];
  const float* W1   = (const float*)d_in[1];   // 1025 x 1024
  const float* b1   = (const float*)d_in[2];
  const float* W2   = (const float*)d_in[3];
  const float* b2   = (const float*)d_in[4];
  const float* W3   = (const float*)d_in[5];
  const float* b3   = (const float*)d_in[6];
  const float* W1last = W1 + (size_t)1024 * 1024;

  char* ws = (char*)d_ws;
  ushort_t* W1t   = (ushort_t*)(ws);                   // 2 MiB (reused for W3^T at end)
  u8*       W2t8  = (u8*)      (ws + (2ull << 20));    // 1 MiB fp8 x32
  u8*       Bt318 = (u8*)      (ws + (3ull << 20));    // 1 MiB fp8 x32
  float*    c31   = (float*)   (ws + (4ull << 20));    // 4 KiB
  ushort_t* hW1b  = (ushort_t*)(ws + (8ull << 20));    // 16 MiB bf16
  u8*       x1    = (u8*)      (ws + (24ull << 20));   // 8 MiB fp8
  u8*       x2s0  = (u8*)      (ws + (32ull << 20));   // 8 MiB fp8
  u8*       x2s1  = (u8*)      (ws + (40ull << 20));   // 8 MiB fp8
  u8*       x2s2  = (u8*)      (ws + (48ull << 20));   // 8 MiB fp8
  u8*       x2s3  = (u8*)      (ws + (56ull << 20));   // 8 MiB fp8
  ushort_t* XT    = (ushort_t*)(ws + (64ull << 20));   // 16 MiB bf16 (W3b transient)
  ushort_t* GS    = (ushort_t*)d_out;                  // bf16, d_out low half
  ushort_t* hb    = (ushort_t*)d_out;                  // bf16 h (dead after MODE1)
  float*    OUT   = (float*)d_out;

  const float dt = 0.1f;
  constexpr int GRID = 512, BLK = 256;
  dim3 tb(32, 8), tg(32, 32);

  // ---- precompute ----
  transpose_bf16<<<tg, tb, 0, stream>>>(W1, W1t);
  transpose_fp8 <<<tg, tb, 0, stream>>>(W2, W2t8);
  conv_bf16<<<1024, 256, 0, stream>>>(W3, XT);         // W3b transient in XT slot
  conv_bf16<<<8192, 256, 0, stream>>>(h_in, hb);
  c31_kernel<<<4, 256, 0, stream>>>(W1t, b3, c31);
  gemm_bf16<0><<<64, BLK, 0, stream>>>(W1t, XT, nullptr, nullptr, Bt318, nullptr, nullptr);
  gemm_bf16<1><<<GRID, BLK, 0, stream>>>(hb, W1t, b1, hW1b, x1, nullptr, nullptr);

  for (int step = 0; step < 10; ++step) {
    const float t0 = step * dt;
    // stage 1
    gemm_fp8<2><<<GRID, BLK, 0, stream>>>(x1, W2t8, b2, nullptr, nullptr, nullptr, nullptr,
                                          nullptr, nullptr, nullptr, x2s0, nullptr, nullptr,
                                          0.f, 0.f, 0.f, 0);
    gemm_fp8<3><<<GRID, BLK, 0, stream>>>(x2s0, Bt318, b1, W1last, c31, hW1b, nullptr,
                                          nullptr, nullptr, nullptr, x1, GS, nullptr,
                                          1.f, 0.5f * dt, t0 + 0.5f * dt, 1);
    // stage 2
    gemm_fp8<2><<<GRID, BLK, 0, stream>>>(x1, W2t8, b2, nullptr, nullptr, nullptr, nullptr,
                                          nullptr, nullptr, nullptr, x2s1, nullptr, nullptr,
                                          0.f, 0.f, 0.f, 0);
    gemm_fp8<3><<<GRID, BLK, 0, stream>>>(x2s1, Bt318, b1, W1last, c31, hW1b, nullptr,
                                          nullptr, nullptr, nullptr, x1, GS, nullptr,
                                          2.f, 0.5f * dt, t0 + 0.5f * dt, 0);
    // stage 3
    gemm_fp8<2><<<GRID, BLK, 0, stream>>>(x1, W2t8, b2, nullptr, nullptr, nullptr, nullptr,
                                          nullptr, nullptr, nullptr, x2s2, nullptr, nullptr,
                                          0.f, 0.f, 0.f, 0);
    gemm_fp8<3><<<GRID, BLK, 0, stream>>>(x2s2, Bt318, b1, W1last, c31, hW1b, nullptr,
                                          nullptr, nullptr, nullptr, x1, GS, nullptr,
                                          2.f, dt, t0 + dt, 0);
    // stage 4
    gemm_fp8<2><<<GRID, BLK, 0, stream>>>(x1, W2t8, b2, nullptr, nullptr, nullptr, nullptr,
                                          nullptr, nullptr, nullptr, x2s3, nullptr, nullptr,
                                          0.f, 0.f, 0.f, 0);
    if (step < 9) {
      gemm_fp8<4><<<GRID, BLK, 0, stream>>>(x2s3, Bt318, b1, W1last, c31, hW1b, GS,
                                            x2s0, x2s1, x2s2, x1, XT, hW1b,
                                            0.f, 0.f, t0 + dt, (step == 0));
    }
  }
  // step-9 XT contribution (no MODE4 needed — hW1 no longer used)
  xtfold<<<4096, 256, 0, stream>>>(x2s0, x2s1, x2s2, x2s3, XT);

  // final: h = h0 + dt/6 * XT@W3 + b3
  transpose_bf16<<<tg, tb, 0, stream>>>(W3, W1t);
  gemm_bf16<5><<<GRID, BLK, 0, stream>>>(XT, W1t, b3, nullptr, nullptr, h_in, OUT);
}